// Round 2
// baseline (4758.077 us; speedup 1.0000x reference)
//
#include <hip/hip_runtime.h>

typedef unsigned short u16;
typedef unsigned int u32;
typedef unsigned long long u64;

// ---------- helpers ----------
__device__ __forceinline__ float bf2f(u16 u) {
  return __uint_as_float(((u32)u) << 16);
}
__device__ __forceinline__ float ld1(const void* p, int isbf, long idx) {
  return isbf ? bf2f(((const u16*)p)[idx]) : ((const float*)p)[idx];
}
// load 4 consecutive elems at flat offset `base`; column index gc guarded against `bound`
__device__ __forceinline__ void ld4(const void* p, int isbf, long base, long gc, long bound, float v[4]) {
  if (gc + 3 < bound && ((base & 3) == 0)) {
    if (isbf) {
      const ushort4 u = *(const ushort4*)((const u16*)p + base);
      v[0] = bf2f(u.x); v[1] = bf2f(u.y); v[2] = bf2f(u.z); v[3] = bf2f(u.w);
    } else {
      const float4 f = *(const float4*)((const float*)p + base);
      v[0] = f.x; v[1] = f.y; v[2] = f.z; v[3] = f.w;
    }
  } else {
    #pragma unroll
    for (int d = 0; d < 4; ++d) v[d] = (gc + d < bound) ? ld1(p, isbf, base + d) : 0.f;
  }
}

// ---------- input dtype autodetect ----------
// adj entries are exactly {0.0, 1.0}. In f32 storage every u32 word is
// 0x00000000 or 0x3F800000. In bf16 storage words 0x00003F80 / 0x3F803F80
// occur ~65k times. Presence of either => bf16 inputs.
__global__ void detect_init_k(int* flag) { if (threadIdx.x == 0 && blockIdx.x == 0) *flag = 0; }

__global__ void detect_k(const u32* __restrict__ a, long nw, int* __restrict__ flag) {
  long stride = (long)gridDim.x * 256;
  int f = 0;
  for (long j = (long)blockIdx.x * 256 + threadIdx.x; j < nw; j += stride) {
    u32 w = a[j];
    if (w == 0x00003F80u || w == 0x3F803F80u) f = 1;
  }
  if (__any(f)) {
    if ((threadIdx.x & 63) == 0) atomicOr(flag, 1);
  }
}

__device__ __forceinline__ int get_bf(int abf, const int* dtf) {
  return (abf >= 0) ? abf : *dtf;
}

// ---------- fp32 GEMM, 128x128 tile, 8x8 per thread (augment products) ----------
__global__ __launch_bounds__(256) void gemm128_f32(
    const void* __restrict__ Ap, long lda, int abf,
    const void* __restrict__ Bp, long ldb, int bbf,
    float* __restrict__ C, long ldc, int M, int N, int K,
    const int* __restrict__ dtf)
{
  const int abf_ = get_bf(abf, dtf);
  const int bbf_ = get_bf(bbf, dtf);
  __shared__ float As[8][128];
  __shared__ float Bs[8][128];
  const int tid = threadIdx.x;
  const int tr = tid >> 4, tc = tid & 15;
  const long row0 = (long)blockIdx.y * 128;
  const long col0 = (long)blockIdx.x * 128;
  float acc[8][8];
  #pragma unroll
  for (int i = 0; i < 8; ++i)
    #pragma unroll
    for (int j = 0; j < 8; ++j) acc[i][j] = 0.f;

  const int am = tid >> 1;         // 0..127
  const int ak = (tid & 1) * 4;    // 0 or 4
  const int bk = tid >> 5;         // 0..7
  const int bn = (tid & 31) * 4;   // 0..124

  for (int k0 = 0; k0 < K; k0 += 8) {
    float va[4] = {0.f, 0.f, 0.f, 0.f};
    {
      long gm = row0 + am; long gk = k0 + ak;
      if (gm < M && gk < K) ld4(Ap, abf_, gm * lda + gk, gk, K, va);
    }
    As[ak + 0][am] = va[0]; As[ak + 1][am] = va[1];
    As[ak + 2][am] = va[2]; As[ak + 3][am] = va[3];

    float vb[4] = {0.f, 0.f, 0.f, 0.f};
    {
      long gk = k0 + bk; long gn = col0 + bn;
      if (gk < K && gn < N) ld4(Bp, bbf_, gk * ldb + gn, gn, N, vb);
    }
    Bs[bk][bn + 0] = vb[0]; Bs[bk][bn + 1] = vb[1];
    Bs[bk][bn + 2] = vb[2]; Bs[bk][bn + 3] = vb[3];

    __syncthreads();
    #pragma unroll
    for (int kk = 0; kk < 8; ++kk) {
      float a[8], b[8];
      #pragma unroll
      for (int i = 0; i < 8; ++i) a[i] = As[kk][tr * 8 + i];
      #pragma unroll
      for (int j = 0; j < 8; ++j) b[j] = Bs[kk][tc * 8 + j];
      #pragma unroll
      for (int i = 0; i < 8; ++i)
        #pragma unroll
        for (int j = 0; j < 8; ++j)
          acc[i][j] = fmaf(a[i], b[j], acc[i][j]);
    }
    __syncthreads();
  }
  #pragma unroll
  for (int i = 0; i < 8; ++i) {
    long gm = row0 + tr * 8 + i;
    if (gm >= M) continue;
    #pragma unroll
    for (int j = 0; j < 8; ++j) {
      long gn = col0 + tc * 8 + j;
      if (gn < N) C[gm * ldc + gn] = acc[i][j];
    }
  }
}

// ---------- fp64-accumulating GEMM, 64x64 tile, 4x4 per thread (feature path) ----------
__global__ __launch_bounds__(256) void gemm64_f64(
    const void* __restrict__ Ap, long lda, int abf,
    const void* __restrict__ Bp, long ldb, int bbf,
    float* __restrict__ C, long ldc, int M, int N, int K,
    const int* __restrict__ dtf)
{
  const int abf_ = get_bf(abf, dtf);
  const int bbf_ = get_bf(bbf, dtf);
  __shared__ float As[16][64];
  __shared__ float Bs[16][64];
  const int tid = threadIdx.x;
  const int tr = tid >> 4, tc = tid & 15;
  const long row0 = (long)blockIdx.y * 64;
  const long col0 = (long)blockIdx.x * 64;
  double acc[4][4];
  #pragma unroll
  for (int i = 0; i < 4; ++i)
    #pragma unroll
    for (int j = 0; j < 4; ++j) acc[i][j] = 0.0;

  const int am = tid >> 2;         // 0..63
  const int ak = (tid & 3) * 4;    // 0..12
  const int bk = tid >> 4;         // 0..15
  const int bn = (tid & 15) * 4;   // 0..60

  for (int k0 = 0; k0 < K; k0 += 16) {
    float va[4] = {0.f, 0.f, 0.f, 0.f};
    {
      long gm = row0 + am; long gk = k0 + ak;
      if (gm < M && gk < K) ld4(Ap, abf_, gm * lda + gk, gk, K, va);
    }
    As[ak + 0][am] = va[0]; As[ak + 1][am] = va[1];
    As[ak + 2][am] = va[2]; As[ak + 3][am] = va[3];

    float vb[4] = {0.f, 0.f, 0.f, 0.f};
    {
      long gk = k0 + bk; long gn = col0 + bn;
      if (gk < K && gn < N) ld4(Bp, bbf_, gk * ldb + gn, gn, N, vb);
    }
    Bs[bk][bn + 0] = vb[0]; Bs[bk][bn + 1] = vb[1];
    Bs[bk][bn + 2] = vb[2]; Bs[bk][bn + 3] = vb[3];

    __syncthreads();
    #pragma unroll
    for (int kk = 0; kk < 16; ++kk) {
      float a[4], b[4];
      #pragma unroll
      for (int i = 0; i < 4; ++i) a[i] = As[kk][tr * 4 + i];
      #pragma unroll
      for (int j = 0; j < 4; ++j) b[j] = Bs[kk][tc * 4 + j];
      #pragma unroll
      for (int i = 0; i < 4; ++i)
        #pragma unroll
        for (int j = 0; j < 4; ++j)
          acc[i][j] += (double)a[i] * (double)b[j];
    }
    __syncthreads();
  }
  #pragma unroll
  for (int i = 0; i < 4; ++i) {
    long gm = row0 + tr * 4 + i;
    if (gm >= M) continue;
    #pragma unroll
    for (int j = 0; j < 4; ++j) {
      long gn = col0 + tc * 4 + j;
      if (gn < N) C[gm * ldc + gn] = (float)acc[i][j];
    }
  }
}

// ---------- small kernels ----------
__global__ void upcast_k(const void* __restrict__ src, float* __restrict__ dst, int n,
                         const int* __restrict__ dtf) {
  int bf = *dtf;
  int i = blockIdx.x * 256 + threadIdx.x;
  if (i < n) dst[i] = ld1(src, bf, i);
}

__global__ void rowsum_dinv_k(const void* __restrict__ A, int abf, int n, float* __restrict__ dinv,
                              const int* __restrict__ dtf) {
  const int bf = get_bf(abf, dtf);
  const int row = blockIdx.x;
  const int tid = threadIdx.x;
  const long base = (long)row * n;
  double s = 0.0;
  for (int j = tid; j < n; j += 256) s += (double)ld1(A, bf, base + j);
  __shared__ double red[256];
  red[tid] = s; __syncthreads();
  for (int st = 128; st > 0; st >>= 1) {
    if (tid < st) red[tid] += red[tid + st];
    __syncthreads();
  }
  if (tid == 0) dinv[row] = (float)(1.0 / sqrt(red[0] + 2.0));
}

__global__ void scale_rows_k(float* __restrict__ Z, const float* __restrict__ dinv, int n, int h) {
  long idx = (long)blockIdx.x * 256 + threadIdx.x;
  if (idx < (long)n * h) Z[idx] *= dinv[idx / h];
}

__global__ void gcn_epi_k(const float* __restrict__ Y, const float* __restrict__ Zs,
                          const float* __restrict__ dinv, const float* __restrict__ b,
                          float* __restrict__ out, int n, int h, int relu) {
  long idx = (long)blockIdx.x * 256 + threadIdx.x;
  if (idx >= (long)n * h) return;
  int i = (int)(idx / h);
  int j = (int)(idx - (long)i * h);
  float v = dinv[i] * (Y[idx] + 2.f * Zs[idx]) + b[j];
  if (relu) v = fmaxf(v, 0.f);
  out[idx] = v;
}

__global__ void aug_epi_k(float* __restrict__ C, const void* __restrict__ A, int abf, int n,
                          const int* __restrict__ dtf) {
  const int bf = get_bf(abf, dtf);
  long idx = (long)blockIdx.x * 256 + threadIdx.x;
  if (idx >= (long)n * n) return;
  long i = idx / n, j = idx - i * n;
  C[idx] = (i == j) ? 0.f : (C[idx] + 2.f * ld1(A, bf, idx));
}

__global__ void pnorm_k(const float* __restrict__ p, int h, double* __restrict__ out) {
  int tid = threadIdx.x;
  double s = 0.0;
  for (int j = tid; j < h; j += 256) { double v = p[j]; s += v * v; }
  __shared__ double red[256];
  red[tid] = s; __syncthreads();
  for (int st = 128; st > 0; st >>= 1) {
    if (tid < st) red[tid] += red[tid + st];
    __syncthreads();
  }
  if (tid == 0) out[0] = sqrt(red[0]);
}

__global__ void score_k(const float* __restrict__ x, int h, const float* __restrict__ pw,
                        const double* __restrict__ pnorm, float* __restrict__ score) {
  int row = blockIdx.x, lane = threadIdx.x;  // block = 64 = one wave
  const long base = (long)row * h;
  double s = 0.0;
  for (int j = lane; j < h; j += 64) s += (double)x[base + j] * (double)pw[j];
  for (int off = 32; off > 0; off >>= 1) s += __shfl_down(s, off);
  if (lane == 0) score[row] = (float)tanh(s / pnorm[0]);
}

// exact jax.lax.top_k: descending value, ascending index on ties; deterministic
__global__ __launch_bounds__(1024) void topk_k(const float* __restrict__ score,
                                               int n, int np2, int k, int* __restrict__ perm) {
  __shared__ u64 keys[4096];
  const int tid = threadIdx.x;
  for (int i = tid; i < np2; i += 1024) {
    u64 key = 0ULL;
    if (i < n) {
      u32 b = __float_as_uint(score[i]);
      u32 u = (b & 0x80000000u) ? ~b : (b | 0x80000000u);
      key = ((u64)u << 32) | (u32)(~(u32)i);
    }
    keys[i] = key;
  }
  __syncthreads();
  for (int size = 2; size <= np2; size <<= 1) {
    for (int stride = size >> 1; stride > 0; stride >>= 1) {
      for (int i = tid; i < np2; i += 1024) {
        int j = i ^ stride;
        if (j > i) {
          u64 a = keys[i], b = keys[j];
          bool up = ((i & size) == 0);  // ascending run
          if (up ? (a > b) : (a < b)) { keys[i] = b; keys[j] = a; }
        }
      }
      __syncthreads();
    }
  }
  // sorted ascending; top-k are the tail, largest first
  for (int r = tid; r < k; r += 1024) {
    u64 kk = keys[np2 - 1 - r];
    perm[r] = (int)(~(u32)(kk & 0xFFFFFFFFull));
  }
}

__global__ void gatherx_k(const float* __restrict__ xsrc, const float* __restrict__ score,
                          const int* __restrict__ perm, int k, int h, float* __restrict__ xdst) {
  long idx = (long)blockIdx.x * 256 + threadIdx.x;
  if (idx >= (long)k * h) return;
  int r = (int)(idx / h);
  int c = (int)(idx - (long)r * h);
  int p = perm[r];
  xdst[idx] = xsrc[(long)p * h + c] * score[p];
}

__global__ void gatherA_k(const float* __restrict__ Asrc, int nsrc,
                          const int* __restrict__ perm, int k, float* __restrict__ Adst) {
  long idx = (long)blockIdx.x * 256 + threadIdx.x;
  if (idx >= (long)k * k) return;
  long r = idx / k, c = idx - r * k;
  Adst[idx] = Asrc[(long)perm[r] * nsrc + perm[c]];
}

__global__ void copy_k(const float* __restrict__ src, float* __restrict__ dst, long n) {
  long idx = (long)blockIdx.x * 256 + threadIdx.x;
  if (idx < n) dst[idx] = src[idx];
}

__global__ void scatter_add_k(float* __restrict__ dst, const int* __restrict__ perm,
                              const float* __restrict__ src, int k, int h) {
  long idx = (long)blockIdx.x * 256 + threadIdx.x;
  if (idx >= (long)k * h) return;
  int r = (int)(idx / h);
  int c = (int)(idx - (long)r * h);
  dst[(long)perm[r] * h + c] += src[idx];  // perm entries unique -> no collisions
}

__global__ void matvec2_k(const void* __restrict__ A, int abf, int n,
                          const float* __restrict__ Zs, float* __restrict__ Y,
                          const int* __restrict__ dtf) {
  const int bf = get_bf(abf, dtf);
  int row = blockIdx.x, tid = threadIdx.x;
  const long base = (long)row * n;
  double s0 = 0.0, s1 = 0.0;
  for (int j = tid; j < n; j += 256) {
    double a = (double)ld1(A, bf, base + j);
    s0 += a * (double)Zs[2 * j];
    s1 += a * (double)Zs[2 * j + 1];
  }
  __shared__ double r0[256], r1[256];
  r0[tid] = s0; r1[tid] = s1; __syncthreads();
  for (int st = 128; st > 0; st >>= 1) {
    if (tid < st) { r0[tid] += r0[tid + st]; r1[tid] += r1[tid + st]; }
    __syncthreads();
  }
  if (tid == 0) { Y[2 * row] = (float)r0[0]; Y[2 * row + 1] = (float)r1[0]; }
}

// output is float32 (reference output dtype)
__global__ void final_k(const float* __restrict__ Y, const float* __restrict__ Zs,
                        const float* __restrict__ dinv, const float* __restrict__ b2,
                        int n, float* __restrict__ out) {
  int i = blockIdx.x * 256 + threadIdx.x;
  if (i >= n) return;
  double di = dinv[i];
  double t0 = di * ((double)Y[2 * i] + 2.0 * (double)Zs[2 * i]) + (double)b2[0];
  double t1 = di * ((double)Y[2 * i + 1] + 2.0 * (double)Zs[2 * i + 1]) + (double)b2[1];
  double m = fmax(t0, t1);
  double l = m + log(exp(t0 - m) + exp(t1 - m));
  out[2 * i] = (float)(t0 - l);
  out[2 * i + 1] = (float)(t1 - l);
}

// ---------- host orchestration ----------
extern "C" void kernel_launch(void* const* d_in, const int* in_sizes, int n_in,
                              void* d_out, int out_size, void* d_ws, size_t ws_size,
                              hipStream_t stream) {
  const int N0 = 4096, H = 200;
  const int K1 = 3072, K2 = 1536, K3 = 768;

  const void* in_x = d_in[0];
  const void* adj  = d_in[1];
  const void* w0 = d_in[2];  const void* b0 = d_in[3];
  const void* w1 = d_in[4];  const void* b1 = d_in[5];
  const void* w2 = d_in[6];  const void* b2 = d_in[7];
  const void* w3 = d_in[8];  const void* b3 = d_in[9];
  const void* p1 = d_in[10]; const void* p2 = d_in[11];
  const void* p3 = d_in[12];
  const void* u0w = d_in[13]; const void* u0b = d_in[14];
  const void* u1w = d_in[15]; const void* u1b = d_in[16];
  const void* u2w = d_in[17]; const void* u2b = d_in[18];

  char* wp = (char*)d_ws;
  auto alloc = [&](size_t bytes) -> void* {
    void* p = (void*)wp;
    wp += (bytes + 255) & ~(size_t)255;
    return p;
  };
  float* Aaug = (float*)alloc((size_t)N0 * N0 * 4);  // augment scratch (reused per level)
  float* As1  = (float*)alloc((size_t)K1 * K1 * 4);
  float* As2  = (float*)alloc((size_t)K2 * K2 * 4);
  float* A3   = (float*)alloc((size_t)K3 * K3 * 4);
  float* xs0  = (float*)alloc((size_t)N0 * H * 4);
  float* xs1  = (float*)alloc((size_t)K1 * H * 4);
  float* xs2  = (float*)alloc((size_t)K2 * H * 4);
  float* xcur = (float*)alloc((size_t)N0 * H * 4);
  float* xtmp = (float*)alloc((size_t)N0 * H * 4);
  float* Zbuf = (float*)alloc((size_t)N0 * H * 4);
  float* Ybuf = (float*)alloc((size_t)N0 * H * 4);
  float* Xinf = (float*)alloc((size_t)N0 * 3 * 4);
  float* dinv0 = (float*)alloc((size_t)N0 * 4);
  float* dinv1 = (float*)alloc((size_t)K1 * 4);
  float* dinv2 = (float*)alloc((size_t)K2 * 4);
  float* dinv3 = (float*)alloc((size_t)K3 * 4);
  float* scores = (float*)alloc((size_t)N0 * 4);
  int* perm1 = (int*)alloc((size_t)K1 * 4);
  int* perm2 = (int*)alloc((size_t)K2 * 4);
  int* perm3 = (int*)alloc((size_t)K3 * 4);
  double* pn = (double*)alloc(8);
  int* dtflag = (int*)alloc(256);
  float* w0f = (float*)alloc(3 * H * 4);  float* b0f = (float*)alloc(H * 4);
  float* w1f = (float*)alloc(H * H * 4);  float* b1f = (float*)alloc(H * 4);
  float* w2f = (float*)alloc(H * H * 4);  float* b2f = (float*)alloc(H * 4);
  float* w3f = (float*)alloc(H * H * 4);  float* b3f = (float*)alloc(H * 4);
  float* p1f = (float*)alloc(H * 4);
  float* p2f = (float*)alloc(H * 4);
  float* p3f = (float*)alloc(H * 4);
  float* u0wf = (float*)alloc(H * H * 4); float* u0bf = (float*)alloc(H * 4);
  float* u1wf = (float*)alloc(H * H * 4); float* u1bf = (float*)alloc(H * 4);
  float* u2wf = (float*)alloc(H * 2 * 4); float* u2bf = (float*)alloc(2 * 4);
  (void)in_sizes; (void)n_in; (void)out_size; (void)ws_size;

  // detect input dtype (bf16 vs f32) from adj bit patterns
  detect_init_k<<<dim3(1), dim3(64), 0, stream>>>(dtflag);
  {
    long nw = (long)N0 * N0 / 2;  // safe word count in both worlds
    detect_k<<<dim3(4096), dim3(256), 0, stream>>>((const u32*)adj, nw, dtflag);
  }

  auto up = [&](const void* s, float* d, int n) {
    upcast_k<<<dim3((n + 255) / 256), dim3(256), 0, stream>>>(s, d, n, dtflag);
  };
  up(in_x, Xinf, N0 * 3);
  up(w0, w0f, 3 * H);  up(b0, b0f, H);
  up(w1, w1f, H * H);  up(b1, b1f, H);
  up(w2, w2f, H * H);  up(b2, b2f, H);
  up(w3, w3f, H * H);  up(b3, b3f, H);
  up(p1, p1f, H); up(p2, p2f, H); up(p3, p3f, H);
  up(u0w, u0wf, H * H); up(u0b, u0bf, H);
  up(u1w, u1wf, H * H); up(u1b, u1bf, H);
  up(u2w, u2wf, H * 2); up(u2b, u2bf, 2);

  auto gemm128 = [&](const void* A, long lda, int abf, const void* B, long ldb, int bbf,
                     float* C, long ldc, int M, int Nn, int K) {
    dim3 g((Nn + 127) / 128, (M + 127) / 128);
    gemm128_f32<<<g, dim3(256), 0, stream>>>(A, lda, abf, B, ldb, bbf, C, ldc, M, Nn, K, dtflag);
  };
  auto gemm64 = [&](const void* A, long lda, int abf, const void* B, long ldb, int bbf,
                    float* C, long ldc, int M, int Nn, int K) {
    dim3 g((Nn + 63) / 64, (M + 63) / 64);
    gemm64_f64<<<g, dim3(256), 0, stream>>>(A, lda, abf, B, ldb, bbf, C, ldc, M, Nn, K, dtflag);
  };

  // GCN: out = maybe_relu( dinv_i * ((A @ (dinv .* (Xin@W)))_i + 2*(dinv.*(Xin@W))_i) + b )
  auto gcn = [&](const void* A, int abf, int n, const float* dinv, const float* Xin_,
                 int din, const float* W, const float* bb, float* out, int relu) {
    gemm64(Xin_, din, 0, W, H, 0, Zbuf, H, n, H, din);        // Z = Xin @ W
    long tot = (long)n * H;
    scale_rows_k<<<dim3((unsigned)((tot + 255) / 256)), dim3(256), 0, stream>>>(Zbuf, dinv, n, H);
    gemm64(A, n, abf, Zbuf, H, 0, Ybuf, H, n, H, n);          // Y = A @ Zs
    gcn_epi_k<<<dim3((unsigned)((tot + 255) / 256)), dim3(256), 0, stream>>>(
        Ybuf, Zbuf, dinv, bb, out, n, H, relu);
  };

  auto pool = [&](const float* xin, int n, int np2, int k, const float* pwf,
                  int* perm, float* xout) {
    pnorm_k<<<dim3(1), dim3(256), 0, stream>>>(pwf, H, pn);
    score_k<<<dim3(n), dim3(64), 0, stream>>>(xin, H, pwf, pn, scores);
    topk_k<<<dim3(1), dim3(1024), 0, stream>>>(scores, n, np2, k, perm);
    long tot = (long)k * H;
    gatherx_k<<<dim3((unsigned)((tot + 255) / 256)), dim3(256), 0, stream>>>(
        xin, scores, perm, k, H, xout);
  };

  auto augment = [&](const void* A, long n, int abf) {
    gemm128(A, n, abf, A, n, abf, Aaug, n, (int)n, (int)n, (int)n);  // Aaug = A@A
    long tot = n * n;
    aug_epi_k<<<dim3((unsigned)((tot + 255) / 256)), dim3(256), 0, stream>>>(
        Aaug, A, abf, (int)n, dtflag);                                // += 2A, zero diag
  };
  auto gatherA = [&](const float* Asrc, int nsrc, const int* perm, int k, float* Adst) {
    long tot = (long)k * k;
    gatherA_k<<<dim3((unsigned)((tot + 255) / 256)), dim3(256), 0, stream>>>(
        Asrc, nsrc, perm, k, Adst);
  };

  // ---------------- forward ----------------
  rowsum_dinv_k<<<dim3(N0), dim3(256), 0, stream>>>(adj, -1, N0, dinv0, dtflag);
  gcn(adj, -1, N0, dinv0, Xinf, 3, w0f, b0f, xs0, 1);         // xs0 = relu(gcn0)

  // down 0
  augment(adj, N0, -1);
  pool(xs0, N0, 4096, K1, p1f, perm1, xcur);
  gatherA(Aaug, N0, perm1, K1, As1);
  rowsum_dinv_k<<<dim3(K1), dim3(256), 0, stream>>>(As1, 0, K1, dinv1, dtflag);
  gcn(As1, 0, K1, dinv1, xcur, H, w1f, b1f, xs1, 1);

  // down 1
  augment(As1, K1, 0);
  pool(xs1, K1, 4096, K2, p2f, perm2, xcur);
  gatherA(Aaug, K1, perm2, K2, As2);
  rowsum_dinv_k<<<dim3(K2), dim3(256), 0, stream>>>(As2, 0, K2, dinv2, dtflag);
  gcn(As2, 0, K2, dinv2, xcur, H, w2f, b2f, xs2, 1);

  // down 2
  augment(As2, K2, 0);
  pool(xs2, K2, 2048, K3, p3f, perm3, xcur);
  gatherA(Aaug, K2, perm3, K3, A3);
  rowsum_dinv_k<<<dim3(K3), dim3(256), 0, stream>>>(A3, 0, K3, dinv3, dtflag);
  gcn(A3, 0, K3, dinv3, xcur, H, w3f, b3f, xcur, 1);          // x (768xH)

  // up 0: j=2
  copy_k<<<dim3((unsigned)(((long)K2 * H + 255) / 256)), dim3(256), 0, stream>>>(xs2, xtmp, (long)K2 * H);
  scatter_add_k<<<dim3((unsigned)(((long)K3 * H + 255) / 256)), dim3(256), 0, stream>>>(xtmp, perm3, xcur, K3, H);
  gcn(As2, 0, K2, dinv2, xtmp, H, u0wf, u0bf, xcur, 1);

  // up 1: j=1
  copy_k<<<dim3((unsigned)(((long)K1 * H + 255) / 256)), dim3(256), 0, stream>>>(xs1, xtmp, (long)K1 * H);
  scatter_add_k<<<dim3((unsigned)(((long)K2 * H + 255) / 256)), dim3(256), 0, stream>>>(xtmp, perm2, xcur, K2, H);
  gcn(As1, 0, K1, dinv1, xtmp, H, u1wf, u1bf, xcur, 1);

  // up 2: j=0 (final GCN, 2 output cols, then log_softmax)
  copy_k<<<dim3((unsigned)(((long)N0 * H + 255) / 256)), dim3(256), 0, stream>>>(xs0, xtmp, (long)N0 * H);
  scatter_add_k<<<dim3((unsigned)(((long)K1 * H + 255) / 256)), dim3(256), 0, stream>>>(xtmp, perm1, xcur, K1, H);
  gemm64(xtmp, H, 0, u2wf, 2, 0, Zbuf, 2, N0, 2, H);          // Z2 = x @ u2w (4096x2)
  scale_rows_k<<<dim3((N0 * 2 + 255) / 256), dim3(256), 0, stream>>>(Zbuf, dinv0, N0, 2);
  matvec2_k<<<dim3(N0), dim3(256), 0, stream>>>(adj, -1, N0, Zbuf, Ybuf, dtflag);
  final_k<<<dim3((N0 + 255) / 256), dim3(256), 0, stream>>>(Ybuf, Zbuf, dinv0, u2bf, N0, (float*)d_out);
}

// Round 3
// 2610.446 us; speedup vs baseline: 1.8227x; 1.8227x over previous
//
#include <hip/hip_runtime.h>

typedef unsigned short u16;
typedef unsigned int u32;
typedef unsigned long long u64;
typedef __attribute__((ext_vector_type(8))) short bfrag8;
typedef __attribute__((ext_vector_type(4))) float f32x4;
typedef __attribute__((address_space(1))) const void gconst_void;
typedef __attribute__((address_space(3))) void lds_void_t;

// ---------- helpers ----------
__device__ __forceinline__ float bf2f(u16 u) {
  return __uint_as_float(((u32)u) << 16);
}
__device__ __forceinline__ u16 f2bf(float f) {
  u32 u = __float_as_uint(f);
  u32 r = (u + 0x7FFFu + ((u >> 16) & 1u)) >> 16;  // RTNE
  return (u16)r;
}
__device__ __forceinline__ float ld1(const void* p, int isbf, long idx) {
  return isbf ? bf2f(((const u16*)p)[idx]) : ((const float*)p)[idx];
}
__device__ __forceinline__ void ld4(const void* p, int isbf, long base, long gc, long bound, float v[4]) {
  if (gc + 3 < bound && ((base & 3) == 0)) {
    if (isbf) {
      const ushort4 u = *(const ushort4*)((const u16*)p + base);
      v[0] = bf2f(u.x); v[1] = bf2f(u.y); v[2] = bf2f(u.z); v[3] = bf2f(u.w);
    } else {
      const float4 f = *(const float4*)((const float*)p + base);
      v[0] = f.x; v[1] = f.y; v[2] = f.z; v[3] = f.w;
    }
  } else {
    #pragma unroll
    for (int d = 0; d < 4; ++d) v[d] = (gc + d < bound) ? ld1(p, isbf, base + d) : 0.f;
  }
}

// ---------- input dtype autodetect (bf16 vs f32) ----------
__global__ void detect_init_k(int* flag) { if (threadIdx.x == 0 && blockIdx.x == 0) *flag = 0; }

__global__ void detect_k(const u32* __restrict__ a, long nw, int* __restrict__ flag) {
  long stride = (long)gridDim.x * 256;
  int f = 0;
  for (long j = (long)blockIdx.x * 256 + threadIdx.x; j < nw; j += stride) {
    u32 w = a[j];
    if (w == 0x00003F80u || w == 0x3F803F80u) f = 1;
  }
  if (__any(f)) {
    if ((threadIdx.x & 63) == 0) atomicOr(flag, 1);
  }
}

__device__ __forceinline__ int get_bf(int abf, const int* dtf) {
  return (abf >= 0) ? abf : *dtf;
}

// ---------- MFMA SYRK: C = Ag @ Ag^T (bf16 in, fp32 out), zero diag ----------
// Requires: M (=N) multiple of 128, K multiple of 32. Ag row-major M x K bf16.
// Exact when Ag entries are integers <= 256 and C entries < 2^24 (our case).
__device__ __forceinline__ void stage16(const u16* g, u16* ldsbase, int lane) {
#if __has_builtin(__builtin_amdgcn_global_load_lds)
  __builtin_amdgcn_global_load_lds((gconst_void*)g, (lds_void_t*)ldsbase, 16, 0, 0);
#else
  *(ushort4*)(ldsbase + lane * 8) = *(const ushort4*)g;
#endif
}

__global__ __launch_bounds__(256) void syrk_bf16_mfma(
    const u16* __restrict__ Ag, int ldk, float* __restrict__ C, int ldc, int K)
{
  __shared__ u16 At[128 * 32];
  __shared__ u16 Bt[128 * 32];
  const int tid = threadIdx.x;
  const int wave = tid >> 6, lane = tid & 63;
  const int wr = wave >> 1, wc = wave & 1;
  const long rowA0 = (long)blockIdx.y * 128;   // C-tile rows (A side)
  const long rowB0 = (long)blockIdx.x * 128;   // C-tile cols (B side = rows of Ag)

  f32x4 acc[4][4];
  #pragma unroll
  for (int i = 0; i < 4; ++i)
    #pragma unroll
    for (int j = 0; j < 4; ++j) acc[i][j] = (f32x4)0.f;

  const int srow = (lane >> 2);        // 0..15 within a 16-row stage
  const int scol = (lane & 3) * 8;     // element col within 32-wide k-tile
  const int m = lane & 15, q = lane >> 4;

  for (int k0 = 0; k0 < K; k0 += 32) {
    #pragma unroll
    for (int t = 0; t < 2; ++t) {
      const int r = wave * 32 + t * 16;               // wave-uniform stage base row
      const u16* ga = Ag + (rowA0 + r + srow) * (long)ldk + k0 + scol;
      const u16* gb = Ag + (rowB0 + r + srow) * (long)ldk + k0 + scol;
      stage16(ga, At + r * 32, lane);
      stage16(gb, Bt + r * 32, lane);
    }
    __syncthreads();

    bfrag8 af[4], bf[4];
    #pragma unroll
    for (int mt = 0; mt < 4; ++mt)
      af[mt] = *(const bfrag8*)(At + (wr * 64 + mt * 16 + m) * 32 + q * 8);
    #pragma unroll
    for (int nt = 0; nt < 4; ++nt)
      bf[nt] = *(const bfrag8*)(Bt + (wc * 64 + nt * 16 + m) * 32 + q * 8);
    #pragma unroll
    for (int mt = 0; mt < 4; ++mt)
      #pragma unroll
      for (int nt = 0; nt < 4; ++nt)
        acc[mt][nt] = __builtin_amdgcn_mfma_f32_16x16x32_bf16(af[mt], bf[nt], acc[mt][nt], 0, 0, 0);
    __syncthreads();
  }

  // C/D layout: col = lane&15, row = (lane>>4)*4 + r  [verified m89/m91]
  #pragma unroll
  for (int mt = 0; mt < 4; ++mt) {
    #pragma unroll
    for (int nt = 0; nt < 4; ++nt) {
      const long gr0 = rowA0 + wr * 64 + mt * 16 + q * 4;
      const long gc = rowB0 + wc * 64 + nt * 16 + m;
      #pragma unroll
      for (int r = 0; r < 4; ++r) {
        const long gr = gr0 + r;
        C[gr * ldc + gc] = (gr == gc) ? 0.f : acc[mt][nt][r];
      }
    }
  }
}

// build Ag (bf16) = src[perm,:] + I : Ag[r][c] = src[perm_r*nsrc+c] + (c==perm_r)
__global__ void build_ag_bf_k(const void* __restrict__ src, int srcbf, int nsrc,
                              const int* __restrict__ perm, long tot, int ld,
                              u16* __restrict__ Ag, const int* __restrict__ dtf) {
  long idx = (long)blockIdx.x * 256 + threadIdx.x;
  if (idx >= tot) return;
  int r = (int)(idx / ld);
  int c = (int)(idx - (long)r * ld);
  int p = perm[r];
  float v = ld1(src, get_bf(srcbf, dtf), (long)p * nsrc + c);
  if (c == p) v += 1.f;
  Ag[idx] = f2bf(v);
}

__global__ void build_ag_f32_k(const float* __restrict__ src, int nsrc,
                               const int* __restrict__ perm, long tot, int ld,
                               float* __restrict__ Ag) {
  long idx = (long)blockIdx.x * 256 + threadIdx.x;
  if (idx >= tot) return;
  int r = (int)(idx / ld);
  int c = (int)(idx - (long)r * ld);
  int p = perm[r];
  float v = src[(long)p * nsrc + c];
  if (c == p) v += 1.f;
  Ag[idx] = v;
}

__global__ void transpose_k(const float* __restrict__ src, float* __restrict__ dst,
                            int rows, int cols) {
  __shared__ float tile[32][33];
  int bx = blockIdx.x * 32, by = blockIdx.y * 32;
  int x = bx + threadIdx.x;
  #pragma unroll
  for (int i = 0; i < 32; i += 8) {
    int y = by + threadIdx.y + i;
    if (x < cols && y < rows) tile[threadIdx.y + i][threadIdx.x] = src[(long)y * cols + x];
  }
  __syncthreads();
  x = by + threadIdx.x;
  #pragma unroll
  for (int i = 0; i < 32; i += 8) {
    int y = bx + threadIdx.y + i;
    if (x < rows && y < cols) dst[(long)y * rows + x] = tile[threadIdx.x][threadIdx.y + i];
  }
}

__global__ void zerodiag_k(float* __restrict__ A, int n) {
  int i = blockIdx.x * 256 + threadIdx.x;
  if (i < n) A[(long)i * n + i] = 0.f;
}

// ---------- fp32 GEMM, 128x128 tile (level-2 fused augment) ----------
__global__ __launch_bounds__(256) void gemm128_f32(
    const void* __restrict__ Ap, long lda, int abf,
    const void* __restrict__ Bp, long ldb, int bbf,
    float* __restrict__ C, long ldc, int M, int N, int K,
    const int* __restrict__ dtf)
{
  const int abf_ = get_bf(abf, dtf);
  const int bbf_ = get_bf(bbf, dtf);
  __shared__ float As[8][128];
  __shared__ float Bs[8][128];
  const int tid = threadIdx.x;
  const int tr = tid >> 4, tc = tid & 15;
  const long row0 = (long)blockIdx.y * 128;
  const long col0 = (long)blockIdx.x * 128;
  float acc[8][8];
  #pragma unroll
  for (int i = 0; i < 8; ++i)
    #pragma unroll
    for (int j = 0; j < 8; ++j) acc[i][j] = 0.f;

  const int am = tid >> 1;
  const int ak = (tid & 1) * 4;
  const int bk = tid >> 5;
  const int bn = (tid & 31) * 4;

  for (int k0 = 0; k0 < K; k0 += 8) {
    float va[4] = {0.f, 0.f, 0.f, 0.f};
    {
      long gm = row0 + am; long gk = k0 + ak;
      if (gm < M && gk < K) ld4(Ap, abf_, gm * lda + gk, gk, K, va);
    }
    As[ak + 0][am] = va[0]; As[ak + 1][am] = va[1];
    As[ak + 2][am] = va[2]; As[ak + 3][am] = va[3];

    float vb[4] = {0.f, 0.f, 0.f, 0.f};
    {
      long gk = k0 + bk; long gn = col0 + bn;
      if (gk < K && gn < N) ld4(Bp, bbf_, gk * ldb + gn, gn, N, vb);
    }
    Bs[bk][bn + 0] = vb[0]; Bs[bk][bn + 1] = vb[1];
    Bs[bk][bn + 2] = vb[2]; Bs[bk][bn + 3] = vb[3];

    __syncthreads();
    #pragma unroll
    for (int kk = 0; kk < 8; ++kk) {
      float a[8], b[8];
      #pragma unroll
      for (int i = 0; i < 8; ++i) a[i] = As[kk][tr * 8 + i];
      #pragma unroll
      for (int j = 0; j < 8; ++j) b[j] = Bs[kk][tc * 8 + j];
      #pragma unroll
      for (int i = 0; i < 8; ++i)
        #pragma unroll
        for (int j = 0; j < 8; ++j)
          acc[i][j] = fmaf(a[i], b[j], acc[i][j]);
    }
    __syncthreads();
  }
  #pragma unroll
  for (int i = 0; i < 8; ++i) {
    long gm = row0 + tr * 8 + i;
    if (gm >= M) continue;
    #pragma unroll
    for (int j = 0; j < 8; ++j) {
      long gn = col0 + tc * 8 + j;
      if (gn < N) C[gm * ldc + gn] = acc[i][j];
    }
  }
}

// ---------- fp64-accumulating GEMM, 64x64 tile (feature path) ----------
__global__ __launch_bounds__(256) void gemm64_f64(
    const void* __restrict__ Ap, long lda, int abf,
    const void* __restrict__ Bp, long ldb, int bbf,
    float* __restrict__ C, long ldc, int M, int N, int K,
    const int* __restrict__ dtf)
{
  const int abf_ = get_bf(abf, dtf);
  const int bbf_ = get_bf(bbf, dtf);
  __shared__ float As[16][64];
  __shared__ float Bs[16][64];
  const int tid = threadIdx.x;
  const int tr = tid >> 4, tc = tid & 15;
  const long row0 = (long)blockIdx.y * 64;
  const long col0 = (long)blockIdx.x * 64;
  double acc[4][4];
  #pragma unroll
  for (int i = 0; i < 4; ++i)
    #pragma unroll
    for (int j = 0; j < 4; ++j) acc[i][j] = 0.0;

  const int am = tid >> 2;
  const int ak = (tid & 3) * 4;
  const int bk = tid >> 4;
  const int bn = (tid & 15) * 4;

  for (int k0 = 0; k0 < K; k0 += 16) {
    float va[4] = {0.f, 0.f, 0.f, 0.f};
    {
      long gm = row0 + am; long gk = k0 + ak;
      if (gm < M && gk < K) ld4(Ap, abf_, gm * lda + gk, gk, K, va);
    }
    As[ak + 0][am] = va[0]; As[ak + 1][am] = va[1];
    As[ak + 2][am] = va[2]; As[ak + 3][am] = va[3];

    float vb[4] = {0.f, 0.f, 0.f, 0.f};
    {
      long gk = k0 + bk; long gn = col0 + bn;
      if (gk < K && gn < N) ld4(Bp, bbf_, gk * ldb + gn, gn, N, vb);
    }
    Bs[bk][bn + 0] = vb[0]; Bs[bk][bn + 1] = vb[1];
    Bs[bk][bn + 2] = vb[2]; Bs[bk][bn + 3] = vb[3];

    __syncthreads();
    #pragma unroll
    for (int kk = 0; kk < 16; ++kk) {
      float a[4], b[4];
      #pragma unroll
      for (int i = 0; i < 4; ++i) a[i] = As[kk][tr * 4 + i];
      #pragma unroll
      for (int j = 0; j < 4; ++j) b[j] = Bs[kk][tc * 4 + j];
      #pragma unroll
      for (int i = 0; i < 4; ++i)
        #pragma unroll
        for (int j = 0; j < 4; ++j)
          acc[i][j] += (double)a[i] * (double)b[j];
    }
    __syncthreads();
  }
  #pragma unroll
  for (int i = 0; i < 4; ++i) {
    long gm = row0 + tr * 4 + i;
    if (gm >= M) continue;
    #pragma unroll
    for (int j = 0; j < 4; ++j) {
      long gn = col0 + tc * 4 + j;
      if (gn < N) C[gm * ldc + gn] = (float)acc[i][j];
    }
  }
}

// ---------- small kernels ----------
__global__ void upcast_k(const void* __restrict__ src, float* __restrict__ dst, int n,
                         const int* __restrict__ dtf) {
  int bf = *dtf;
  int i = blockIdx.x * 256 + threadIdx.x;
  if (i < n) dst[i] = ld1(src, bf, i);
}

__global__ void rowsum_dinv_k(const void* __restrict__ A, int abf, int n, float* __restrict__ dinv,
                              const int* __restrict__ dtf) {
  const int bf = get_bf(abf, dtf);
  const int row = blockIdx.x;
  const int tid = threadIdx.x;
  const long base = (long)row * n;
  double s = 0.0;
  for (int j = tid; j < n; j += 256) s += (double)ld1(A, bf, base + j);
  __shared__ double red[256];
  red[tid] = s; __syncthreads();
  for (int st = 128; st > 0; st >>= 1) {
    if (tid < st) red[tid] += red[tid + st];
    __syncthreads();
  }
  if (tid == 0) dinv[row] = (float)(1.0 / sqrt(red[0] + 2.0));
}

__global__ void scale_rows_k(float* __restrict__ Z, const float* __restrict__ dinv, int n, int h) {
  long idx = (long)blockIdx.x * 256 + threadIdx.x;
  if (idx < (long)n * h) Z[idx] *= dinv[idx / h];
}

__global__ void gcn_epi_k(const float* __restrict__ Y, const float* __restrict__ Zs,
                          const float* __restrict__ dinv, const float* __restrict__ b,
                          float* __restrict__ out, int n, int h, int relu) {
  long idx = (long)blockIdx.x * 256 + threadIdx.x;
  if (idx >= (long)n * h) return;
  int i = (int)(idx / h);
  int j = (int)(idx - (long)i * h);
  float v = dinv[i] * (Y[idx] + 2.f * Zs[idx]) + b[j];
  if (relu) v = fmaxf(v, 0.f);
  out[idx] = v;
}

__global__ void pnorm_k(const float* __restrict__ p, int h, double* __restrict__ out) {
  int tid = threadIdx.x;
  double s = 0.0;
  for (int j = tid; j < h; j += 256) { double v = p[j]; s += v * v; }
  __shared__ double red[256];
  red[tid] = s; __syncthreads();
  for (int st = 128; st > 0; st >>= 1) {
    if (tid < st) red[tid] += red[tid + st];
    __syncthreads();
  }
  if (tid == 0) out[0] = sqrt(red[0]);
}

__global__ void score_k(const float* __restrict__ x, int h, const float* __restrict__ pw,
                        const double* __restrict__ pnorm, float* __restrict__ score) {
  int row = blockIdx.x, lane = threadIdx.x;  // block = 64 = one wave
  const long base = (long)row * h;
  double s = 0.0;
  for (int j = lane; j < h; j += 64) s += (double)x[base + j] * (double)pw[j];
  for (int off = 32; off > 0; off >>= 1) s += __shfl_down(s, off);
  if (lane == 0) score[row] = (float)tanh(s / pnorm[0]);
}

// exact jax.lax.top_k order: descending value, ascending index on ties
__global__ __launch_bounds__(1024) void topk_k(const float* __restrict__ score,
                                               int n, int np2, int k, int* __restrict__ perm) {
  __shared__ u64 keys[4096];
  const int tid = threadIdx.x;
  for (int i = tid; i < np2; i += 1024) {
    u64 key = 0ULL;
    if (i < n) {
      u32 b = __float_as_uint(score[i]);
      u32 u = (b & 0x80000000u) ? ~b : (b | 0x80000000u);
      key = ((u64)u << 32) | (u32)(~(u32)i);
    }
    keys[i] = key;
  }
  __syncthreads();
  for (int size = 2; size <= np2; size <<= 1) {
    for (int stride = size >> 1; stride > 0; stride >>= 1) {
      for (int i = tid; i < np2; i += 1024) {
        int j = i ^ stride;
        if (j > i) {
          u64 a = keys[i], b = keys[j];
          bool up = ((i & size) == 0);
          if (up ? (a > b) : (a < b)) { keys[i] = b; keys[j] = a; }
        }
      }
      __syncthreads();
    }
  }
  for (int r = tid; r < k; r += 1024) {
    u64 kk = keys[np2 - 1 - r];
    perm[r] = (int)(~(u32)(kk & 0xFFFFFFFFull));
  }
}

__global__ void gatherx_k(const float* __restrict__ xsrc, const float* __restrict__ score,
                          const int* __restrict__ perm, int k, int h, float* __restrict__ xdst) {
  long idx = (long)blockIdx.x * 256 + threadIdx.x;
  if (idx >= (long)k * h) return;
  int r = (int)(idx / h);
  int c = (int)(idx - (long)r * h);
  int p = perm[r];
  xdst[idx] = xsrc[(long)p * h + c] * score[p];
}

__global__ void copy_k(const float* __restrict__ src, float* __restrict__ dst, long n) {
  long idx = (long)blockIdx.x * 256 + threadIdx.x;
  if (idx < n) dst[idx] = src[idx];
}

__global__ void scatter_add_k(float* __restrict__ dst, const int* __restrict__ perm,
                              const float* __restrict__ src, int k, int h) {
  long idx = (long)blockIdx.x * 256 + threadIdx.x;
  if (idx >= (long)k * h) return;
  int r = (int)(idx / h);
  int c = (int)(idx - (long)r * h);
  dst[(long)perm[r] * h + c] += src[idx];
}

__global__ void matvec2_k(const void* __restrict__ A, int abf, int n,
                          const float* __restrict__ Zs, float* __restrict__ Y,
                          const int* __restrict__ dtf) {
  const int bf = get_bf(abf, dtf);
  int row = blockIdx.x, tid = threadIdx.x;
  const long base = (long)row * n;
  double s0 = 0.0, s1 = 0.0;
  for (int j = tid; j < n; j += 256) {
    double a = (double)ld1(A, bf, base + j);
    s0 += a * (double)Zs[2 * j];
    s1 += a * (double)Zs[2 * j + 1];
  }
  __shared__ double r0[256], r1[256];
  r0[tid] = s0; r1[tid] = s1; __syncthreads();
  for (int st = 128; st > 0; st >>= 1) {
    if (tid < st) { r0[tid] += r0[tid + st]; r1[tid] += r1[tid + st]; }
    __syncthreads();
  }
  if (tid == 0) { Y[2 * row] = (float)r0[0]; Y[2 * row + 1] = (float)r1[0]; }
}

__global__ void final_k(const float* __restrict__ Y, const float* __restrict__ Zs,
                        const float* __restrict__ dinv, const float* __restrict__ b2,
                        int n, float* __restrict__ out) {
  int i = blockIdx.x * 256 + threadIdx.x;
  if (i >= n) return;
  double di = dinv[i];
  double t0 = di * ((double)Y[2 * i] + 2.0 * (double)Zs[2 * i]) + (double)b2[0];
  double t1 = di * ((double)Y[2 * i + 1] + 2.0 * (double)Zs[2 * i + 1]) + (double)b2[1];
  double m = fmax(t0, t1);
  double l = m + log(exp(t0 - m) + exp(t1 - m));
  out[2 * i] = (float)(t0 - l);
  out[2 * i + 1] = (float)(t1 - l);
}

// ---------- host orchestration ----------
extern "C" void kernel_launch(void* const* d_in, const int* in_sizes, int n_in,
                              void* d_out, int out_size, void* d_ws, size_t ws_size,
                              hipStream_t stream) {
  const int N0 = 4096, H = 200;
  const int K1 = 3072, K2 = 1536, K3 = 768;

  const void* in_x = d_in[0];
  const void* adj  = d_in[1];
  const void* w0 = d_in[2];  const void* b0 = d_in[3];
  const void* w1 = d_in[4];  const void* b1 = d_in[5];
  const void* w2 = d_in[6];  const void* b2 = d_in[7];
  const void* w3 = d_in[8];  const void* b3 = d_in[9];
  const void* p1 = d_in[10]; const void* p2 = d_in[11];
  const void* p3 = d_in[12];
  const void* u0w = d_in[13]; const void* u0b = d_in[14];
  const void* u1w = d_in[15]; const void* u1b = d_in[16];
  const void* u2w = d_in[17]; const void* u2b = d_in[18];

  char* wp = (char*)d_ws;
  auto alloc = [&](size_t bytes) -> void* {
    void* p = (void*)wp;
    wp += (bytes + 255) & ~(size_t)255;
    return p;
  };
  float* As1  = (float*)alloc((size_t)K1 * K1 * 4);          // 37.7 MB
  float* As2  = (float*)alloc((size_t)K2 * K2 * 4);          // 9.4 MB
  float* A3   = (float*)alloc((size_t)K3 * K3 * 4);          // 2.4 MB
  u16*   Agb  = (u16*)alloc((size_t)K1 * N0 * 2);            // 25.2 MB (bf16 gathered Ap rows)
  float* Ag3f = (float*)alloc((size_t)K3 * K2 * 4);          // 4.7 MB
  float* Ag3T = (float*)alloc((size_t)K2 * K3 * 4);          // 4.7 MB
  float* xs0  = (float*)alloc((size_t)N0 * H * 4);
  float* xs1  = (float*)alloc((size_t)K1 * H * 4);
  float* xs2  = (float*)alloc((size_t)K2 * H * 4);
  float* xcur = (float*)alloc((size_t)N0 * H * 4);
  float* xtmp = (float*)alloc((size_t)N0 * H * 4);
  float* Zbuf = (float*)alloc((size_t)N0 * H * 4);
  float* Ybuf = (float*)alloc((size_t)N0 * H * 4);
  float* Xinf = (float*)alloc((size_t)N0 * 3 * 4);
  float* dinv0 = (float*)alloc((size_t)N0 * 4);
  float* dinv1 = (float*)alloc((size_t)K1 * 4);
  float* dinv2 = (float*)alloc((size_t)K2 * 4);
  float* dinv3 = (float*)alloc((size_t)K3 * 4);
  float* scores = (float*)alloc((size_t)N0 * 4);
  int* perm1 = (int*)alloc((size_t)K1 * 4);
  int* perm2 = (int*)alloc((size_t)K2 * 4);
  int* perm3 = (int*)alloc((size_t)K3 * 4);
  double* pn = (double*)alloc(8);
  int* dtflag = (int*)alloc(256);
  float* w0f = (float*)alloc(3 * H * 4);  float* b0f = (float*)alloc(H * 4);
  float* w1f = (float*)alloc(H * H * 4);  float* b1f = (float*)alloc(H * 4);
  float* w2f = (float*)alloc(H * H * 4);  float* b2f = (float*)alloc(H * 4);
  float* w3f = (float*)alloc(H * H * 4);  float* b3f = (float*)alloc(H * 4);
  float* p1f = (float*)alloc(H * 4);
  float* p2f = (float*)alloc(H * 4);
  float* p3f = (float*)alloc(H * 4);
  float* u0wf = (float*)alloc(H * H * 4); float* u0bf = (float*)alloc(H * 4);
  float* u1wf = (float*)alloc(H * H * 4); float* u1bf = (float*)alloc(H * 4);
  float* u2wf = (float*)alloc(H * 2 * 4); float* u2bf = (float*)alloc(2 * 4);
  (void)in_sizes; (void)n_in; (void)out_size; (void)ws_size;

  // detect input dtype (bf16 vs f32) from adj bit patterns
  detect_init_k<<<dim3(1), dim3(64), 0, stream>>>(dtflag);
  detect_k<<<dim3(4096), dim3(256), 0, stream>>>((const u32*)adj, (long)N0 * N0 / 2, dtflag);

  auto up = [&](const void* s, float* d, int n) {
    upcast_k<<<dim3((n + 255) / 256), dim3(256), 0, stream>>>(s, d, n, dtflag);
  };
  up(in_x, Xinf, N0 * 3);
  up(w0, w0f, 3 * H);  up(b0, b0f, H);
  up(w1, w1f, H * H);  up(b1, b1f, H);
  up(w2, w2f, H * H);  up(b2, b2f, H);
  up(w3, w3f, H * H);  up(b3, b3f, H);
  up(p1, p1f, H); up(p2, p2f, H); up(p3, p3f, H);
  up(u0w, u0wf, H * H); up(u0b, u0bf, H);
  up(u1w, u1wf, H * H); up(u1b, u1bf, H);
  up(u2w, u2wf, H * 2); up(u2b, u2bf, 2);

  auto gemm64 = [&](const void* A, long lda, int abf, const void* B, long ldb, int bbf,
                    float* C, long ldc, int M, int Nn, int K) {
    dim3 g((Nn + 63) / 64, (M + 63) / 64);
    gemm64_f64<<<g, dim3(256), 0, stream>>>(A, lda, abf, B, ldb, bbf, C, ldc, M, Nn, K, dtflag);
  };

  auto gcn = [&](const void* A, int abf, int n, const float* dinv, const float* Xin_,
                 int din, const float* W, const float* bb, float* out, int relu) {
    gemm64(Xin_, din, 0, W, H, 0, Zbuf, H, n, H, din);        // Z = Xin @ W
    long tot = (long)n * H;
    scale_rows_k<<<dim3((unsigned)((tot + 255) / 256)), dim3(256), 0, stream>>>(Zbuf, dinv, n, H);
    gemm64(A, n, abf, Zbuf, H, 0, Ybuf, H, n, H, n);          // Y = A @ Zs
    gcn_epi_k<<<dim3((unsigned)((tot + 255) / 256)), dim3(256), 0, stream>>>(
        Ybuf, Zbuf, dinv, bb, out, n, H, relu);
  };

  auto pool = [&](const float* xin, int n, int np2, int k, const float* pwf,
                  int* perm, float* xout) {
    pnorm_k<<<dim3(1), dim3(256), 0, stream>>>(pwf, H, pn);
    score_k<<<dim3(n), dim3(64), 0, stream>>>(xin, H, pwf, pn, scores);
    topk_k<<<dim3(1), dim3(1024), 0, stream>>>(scores, n, np2, k, perm);
    long tot = (long)k * H;
    gatherx_k<<<dim3((unsigned)((tot + 255) / 256)), dim3(256), 0, stream>>>(
        xin, scores, perm, k, H, xout);
  };

  // fused pooled augment (bf16 MFMA, exact): dst = ((src+I)[perm] @ (src+I)[perm]^T), diag 0
  auto fused_aug_bf = [&](const void* src, int srcbf, int nsrc, const int* perm, int k,
                          float* dst) {
    long tot = (long)k * nsrc;
    build_ag_bf_k<<<dim3((unsigned)((tot + 255) / 256)), dim3(256), 0, stream>>>(
        src, srcbf, nsrc, perm, tot, nsrc, Agb, dtflag);
    dim3 g(k / 128, k / 128);
    syrk_bf16_mfma<<<g, dim3(256), 0, stream>>>(Agb, nsrc, dst, k, nsrc);
  };

  // ---------------- forward ----------------
  rowsum_dinv_k<<<dim3(N0), dim3(256), 0, stream>>>(adj, -1, N0, dinv0, dtflag);
  gcn(adj, -1, N0, dinv0, Xinf, 3, w0f, b0f, xs0, 1);         // xs0 = relu(gcn0)

  // down 0: pool scores from xs0, then fused augment+gather
  pool(xs0, N0, 4096, K1, p1f, perm1, xcur);
  fused_aug_bf(adj, -1, N0, perm1, K1, As1);
  rowsum_dinv_k<<<dim3(K1), dim3(256), 0, stream>>>(As1, 0, K1, dinv1, dtflag);
  gcn(As1, 0, K1, dinv1, xcur, H, w1f, b1f, xs1, 1);

  // down 1
  pool(xs1, K1, 4096, K2, p2f, perm2, xcur);
  fused_aug_bf(As1, 0, K1, perm2, K2, As2);
  rowsum_dinv_k<<<dim3(K2), dim3(256), 0, stream>>>(As2, 0, K2, dinv2, dtflag);
  gcn(As2, 0, K2, dinv2, xcur, H, w2f, b2f, xs2, 1);

  // down 2 (entries can exceed 256 -> not bf16-exact -> fp32 vector path)
  pool(xs2, K2, 2048, K3, p3f, perm3, xcur);
  {
    long tot = (long)K3 * K2;
    build_ag_f32_k<<<dim3((unsigned)((tot + 255) / 256)), dim3(256), 0, stream>>>(
        As2, K2, perm3, tot, K2, Ag3f);
    transpose_k<<<dim3(K2 / 32, K3 / 32), dim3(32, 8), 0, stream>>>(Ag3f, Ag3T, K3, K2);
    gemm128_f32<<<dim3(K3 / 128, K3 / 128), dim3(256), 0, stream>>>(
        Ag3f, K2, 0, Ag3T, K3, 0, A3, K3, K3, K3, K2, dtflag);
    zerodiag_k<<<dim3((K3 + 255) / 256), dim3(256), 0, stream>>>(A3, K3);
  }
  rowsum_dinv_k<<<dim3(K3), dim3(256), 0, stream>>>(A3, 0, K3, dinv3, dtflag);
  gcn(A3, 0, K3, dinv3, xcur, H, w3f, b3f, xcur, 1);          // x (768xH)

  // up 0: j=2
  copy_k<<<dim3((unsigned)(((long)K2 * H + 255) / 256)), dim3(256), 0, stream>>>(xs2, xtmp, (long)K2 * H);
  scatter_add_k<<<dim3((unsigned)(((long)K3 * H + 255) / 256)), dim3(256), 0, stream>>>(xtmp, perm3, xcur, K3, H);
  gcn(As2, 0, K2, dinv2, xtmp, H, u0wf, u0bf, xcur, 1);

  // up 1: j=1
  copy_k<<<dim3((unsigned)(((long)K1 * H + 255) / 256)), dim3(256), 0, stream>>>(xs1, xtmp, (long)K1 * H);
  scatter_add_k<<<dim3((unsigned)(((long)K2 * H + 255) / 256)), dim3(256), 0, stream>>>(xtmp, perm2, xcur, K2, H);
  gcn(As1, 0, K1, dinv1, xtmp, H, u1wf, u1bf, xcur, 1);

  // up 2: j=0 (final GCN, 2 output cols, then log_softmax)
  copy_k<<<dim3((unsigned)(((long)N0 * H + 255) / 256)), dim3(256), 0, stream>>>(xs0, xtmp, (long)N0 * H);
  scatter_add_k<<<dim3((unsigned)(((long)K1 * H + 255) / 256)), dim3(256), 0, stream>>>(xtmp, perm1, xcur, K1, H);
  gemm64(xtmp, H, 0, u2wf, 2, 0, Zbuf, 2, N0, 2, H);
  scale_rows_k<<<dim3((N0 * 2 + 255) / 256), dim3(256), 0, stream>>>(Zbuf, dinv0, N0, 2);
  matvec2_k<<<dim3(N0), dim3(256), 0, stream>>>(adj, -1, N0, Zbuf, Ybuf, dtflag);
  final_k<<<dim3((N0 + 255) / 256), dim3(256), 0, stream>>>(Ybuf, Zbuf, dinv0, u2bf, N0, (float*)d_out);
}

// Round 4
// 1396.706 us; speedup vs baseline: 3.4066x; 1.8690x over previous
//
#include <hip/hip_runtime.h>

typedef unsigned short u16;
typedef unsigned int u32;
typedef unsigned long long u64;
typedef __attribute__((ext_vector_type(8))) short bfrag8;
typedef __attribute__((ext_vector_type(4))) float f32x4;
typedef __attribute__((address_space(1))) const void gconst_void;
typedef __attribute__((address_space(3))) void lds_void_t;

// ---------- helpers ----------
__device__ __forceinline__ float bf2f(u16 u) {
  return __uint_as_float(((u32)u) << 16);
}
__device__ __forceinline__ u16 f2bf(float f) {
  u32 u = __float_as_uint(f);
  u32 r = (u + 0x7FFFu + ((u >> 16) & 1u)) >> 16;  // RTNE
  return (u16)r;
}
__device__ __forceinline__ float ld1(const void* p, int isbf, long idx) {
  return isbf ? bf2f(((const u16*)p)[idx]) : ((const float*)p)[idx];
}
__device__ __forceinline__ void ld4(const void* p, int isbf, long base, long gc, long bound, float v[4]) {
  if (gc + 3 < bound && ((base & 3) == 0)) {
    if (isbf) {
      const ushort4 u = *(const ushort4*)((const u16*)p + base);
      v[0] = bf2f(u.x); v[1] = bf2f(u.y); v[2] = bf2f(u.z); v[3] = bf2f(u.w);
    } else {
      const float4 f = *(const float4*)((const float*)p + base);
      v[0] = f.x; v[1] = f.y; v[2] = f.z; v[3] = f.w;
    }
  } else {
    #pragma unroll
    for (int d = 0; d < 4; ++d) v[d] = (gc + d < bound) ? ld1(p, isbf, base + d) : 0.f;
  }
}

// ---------- input dtype autodetect (bf16 vs f32) ----------
__global__ void detect_init_k(int* flag) { if (threadIdx.x == 0 && blockIdx.x == 0) *flag = 0; }

__global__ void detect_k(const u32* __restrict__ a, long nw, int* __restrict__ flag) {
  long stride = (long)gridDim.x * 256;
  int f = 0;
  for (long j = (long)blockIdx.x * 256 + threadIdx.x; j < nw; j += stride) {
    u32 w = a[j];
    if (w == 0x00003F80u || w == 0x3F803F80u) f = 1;
  }
  if (__any(f)) {
    if ((threadIdx.x & 63) == 0) atomicOr(flag, 1);
  }
}

__device__ __forceinline__ int get_bf(int abf, const int* dtf) {
  return (abf >= 0) ? abf : *dtf;
}

// ---------- async global->LDS stage: 64 lanes x 16B ----------
__device__ __forceinline__ void stage16(const u16* g, u16* ldsbase, int lane) {
#if __has_builtin(__builtin_amdgcn_global_load_lds)
  __builtin_amdgcn_global_load_lds((gconst_void*)g, (lds_void_t*)ldsbase, 16, 0, 0);
#else
  *(ushort4*)(ldsbase + lane * 8) = *(const ushort4*)g;
#endif
}

// ---------- MFMA SYRK: C = Ag @ Ag^T (bf16 in, fp32 out), zero diag ----------
__global__ __launch_bounds__(256) void syrk_bf16_mfma(
    const u16* __restrict__ Ag, int ldk, float* __restrict__ C, int ldc, int K)
{
  __shared__ u16 At[128 * 32];
  __shared__ u16 Bt[128 * 32];
  const int tid = threadIdx.x;
  const int wave = tid >> 6, lane = tid & 63;
  const int wr = wave >> 1, wc = wave & 1;
  const long rowA0 = (long)blockIdx.y * 128;
  const long rowB0 = (long)blockIdx.x * 128;

  f32x4 acc[4][4];
  #pragma unroll
  for (int i = 0; i < 4; ++i)
    #pragma unroll
    for (int j = 0; j < 4; ++j) acc[i][j] = (f32x4)0.f;

  const int srow = (lane >> 2);
  const int scol = (lane & 3) * 8;
  const int m = lane & 15, q = lane >> 4;

  for (int k0 = 0; k0 < K; k0 += 32) {
    #pragma unroll
    for (int t = 0; t < 2; ++t) {
      const int r = wave * 32 + t * 16;
      stage16(Ag + (rowA0 + r + srow) * (long)ldk + k0 + scol, At + r * 32, lane);
      stage16(Ag + (rowB0 + r + srow) * (long)ldk + k0 + scol, Bt + r * 32, lane);
    }
    __syncthreads();

    bfrag8 af[4], bf[4];
    #pragma unroll
    for (int mt = 0; mt < 4; ++mt)
      af[mt] = *(const bfrag8*)(At + (wr * 64 + mt * 16 + m) * 32 + q * 8);
    #pragma unroll
    for (int nt = 0; nt < 4; ++nt)
      bf[nt] = *(const bfrag8*)(Bt + (wc * 64 + nt * 16 + m) * 32 + q * 8);
    #pragma unroll
    for (int mt = 0; mt < 4; ++mt)
      #pragma unroll
      for (int nt = 0; nt < 4; ++nt)
        acc[mt][nt] = __builtin_amdgcn_mfma_f32_16x16x32_bf16(af[mt], bf[nt], acc[mt][nt], 0, 0, 0);
    __syncthreads();
  }

  #pragma unroll
  for (int mt = 0; mt < 4; ++mt) {
    #pragma unroll
    for (int nt = 0; nt < 4; ++nt) {
      const long gr0 = rowA0 + wr * 64 + mt * 16 + q * 4;
      const long gc = rowB0 + wc * 64 + nt * 16 + m;
      #pragma unroll
      for (int r = 0; r < 4; ++r) {
        const long gr = gr0 + r;
        C[gr * ldc + gc] = (gr == gc) ? 0.f : acc[mt][nt][r];
      }
    }
  }
}

// ---------- MFMA aggregation: Y = A @ Z, A exact as Ah(+Al) bf16 planes, ----------
// Z as 3 bf16 planes transposed ([plane*NT16+c][k]); K-split into partial buffers.
template<int NT>
__global__ __launch_bounds__(256) void agg_mfma(
    const u16* __restrict__ Ah, const u16* __restrict__ Al,
    const u16* __restrict__ ZT, float* __restrict__ parts,
    int K, int per_steps)
{
  __shared__ u16 At[128 * 32];
  __shared__ u16 Alt[128 * 32];
  __shared__ u16 Zt[3 * NT * 512];
  const int tid = threadIdx.x;
  const int wave = tid >> 6, lane = tid & 63;
  const long row0 = (long)blockIdx.x * 128;
  const int chunk = blockIdx.y;
  const int kbeg = chunk * per_steps * 32;
  const int kend = min(K, kbeg + per_steps * 32);
  const int m = lane & 15, q = lane >> 4;
  const int srow = lane >> 2, scol = (lane & 3) * 8;
  const bool hasAl = (Al != nullptr);

  f32x4 acc[2][NT];
  #pragma unroll
  for (int rt = 0; rt < 2; ++rt)
    #pragma unroll
    for (int ct = 0; ct < NT; ++ct) acc[rt][ct] = (f32x4)0.f;

  for (int k0 = kbeg; k0 < kend; k0 += 32) {
    #pragma unroll
    for (int t = 0; t < 2; ++t) {
      const int r = wave * 32 + t * 16;
      stage16(Ah + (row0 + r + srow) * (long)K + k0 + scol, At + r * 32, lane);
      if (hasAl)
        stage16(Al + (row0 + r + srow) * (long)K + k0 + scol, Alt + r * 32, lane);
    }
    for (int s = wave; s < 3 * NT; s += 4) {
      const u16* g = ZT + ((long)(s * 16 + srow)) * K + k0 + scol;
      stage16(g, Zt + s * 512, lane);
    }
    __syncthreads();

    bfrag8 af0 = *(const bfrag8*)(At + (wave * 32 + m) * 32 + q * 8);
    bfrag8 af1 = *(const bfrag8*)(At + (wave * 32 + 16 + m) * 32 + q * 8);
    bfrag8 al0, al1;
    if (hasAl) {
      al0 = *(const bfrag8*)(Alt + (wave * 32 + m) * 32 + q * 8);
      al1 = *(const bfrag8*)(Alt + (wave * 32 + 16 + m) * 32 + q * 8);
    }
    #pragma unroll
    for (int ct = 0; ct < NT; ++ct) {
      bfrag8 b0 = *(const bfrag8*)(Zt + (0 * NT + ct) * 512 + m * 32 + q * 8);
      bfrag8 b1 = *(const bfrag8*)(Zt + (1 * NT + ct) * 512 + m * 32 + q * 8);
      bfrag8 b2 = *(const bfrag8*)(Zt + (2 * NT + ct) * 512 + m * 32 + q * 8);
      acc[0][ct] = __builtin_amdgcn_mfma_f32_16x16x32_bf16(af0, b0, acc[0][ct], 0, 0, 0);
      acc[0][ct] = __builtin_amdgcn_mfma_f32_16x16x32_bf16(af0, b1, acc[0][ct], 0, 0, 0);
      acc[0][ct] = __builtin_amdgcn_mfma_f32_16x16x32_bf16(af0, b2, acc[0][ct], 0, 0, 0);
      acc[1][ct] = __builtin_amdgcn_mfma_f32_16x16x32_bf16(af1, b0, acc[1][ct], 0, 0, 0);
      acc[1][ct] = __builtin_amdgcn_mfma_f32_16x16x32_bf16(af1, b1, acc[1][ct], 0, 0, 0);
      acc[1][ct] = __builtin_amdgcn_mfma_f32_16x16x32_bf16(af1, b2, acc[1][ct], 0, 0, 0);
      if (hasAl) {
        acc[0][ct] = __builtin_amdgcn_mfma_f32_16x16x32_bf16(al0, b0, acc[0][ct], 0, 0, 0);
        acc[0][ct] = __builtin_amdgcn_mfma_f32_16x16x32_bf16(al0, b1, acc[0][ct], 0, 0, 0);
        acc[1][ct] = __builtin_amdgcn_mfma_f32_16x16x32_bf16(al1, b0, acc[1][ct], 0, 0, 0);
        acc[1][ct] = __builtin_amdgcn_mfma_f32_16x16x32_bf16(al1, b1, acc[1][ct], 0, 0, 0);
      }
    }
    __syncthreads();
  }

  float* P = parts + (long)chunk * gridDim.x * 128 * (NT * 16);
  #pragma unroll
  for (int rt = 0; rt < 2; ++rt) {
    #pragma unroll
    for (int ct = 0; ct < NT; ++ct) {
      const long grow0 = row0 + wave * 32 + rt * 16 + q * 4;
      const long gcol = ct * 16 + m;
      #pragma unroll
      for (int r = 0; r < 4; ++r)
        P[(grow0 + r) * (NT * 16) + gcol] = acc[rt][ct][r];
    }
  }
}

__global__ void reduce8_k(const float* __restrict__ parts, float* __restrict__ Y, long n208) {
  long idx = (long)blockIdx.x * 256 + threadIdx.x;
  if (idx >= n208) return;
  float s = 0.f;
  #pragma unroll
  for (int c = 0; c < 8; ++c) s += parts[(long)c * n208 + idx];
  Y[idx] = s;
}

// Z (n x 200 f32) -> 3 bf16 planes transposed: ZT[(p*208+c)*n + k], cols 200..207 zero
__global__ void zsplit_k(const float* __restrict__ Z, int n, int h, u16* __restrict__ ZT) {
  __shared__ float t[32][33];
  const int kb = blockIdx.x * 32;
  const int cb = blockIdx.y * 32;
  #pragma unroll
  for (int i = 0; i < 32; i += 8) {
    int k = kb + threadIdx.y + i;
    int c = cb + threadIdx.x;
    t[threadIdx.y + i][threadIdx.x] = (c < h) ? Z[(long)k * h + c] : 0.f;
  }
  __syncthreads();
  #pragma unroll
  for (int i = 0; i < 32; i += 8) {
    int c = cb + threadIdx.y + i;
    if (c >= 208) continue;
    long k = kb + threadIdx.x;
    float v = t[threadIdx.x][threadIdx.y + i];
    u16 hi = f2bf(v); float r1 = v - bf2f(hi);
    u16 mi = f2bf(r1); float r2 = r1 - bf2f(mi);
    u16 lo = f2bf(r2);
    ZT[((long)0 * 208 + c) * n + k] = hi;
    ZT[((long)1 * 208 + c) * n + k] = mi;
    ZT[((long)2 * 208 + c) * n + k] = lo;
  }
}

// split fp32 A into exact bf16 hi/lo planes (Al nullable)
__global__ void asplit_k(const float* __restrict__ src, long tot,
                         u16* __restrict__ Ah, u16* __restrict__ Al) {
  long idx = (long)blockIdx.x * 256 + threadIdx.x;
  if (idx >= tot) return;
  float v = src[idx];
  u16 h = f2bf(v);
  Ah[idx] = h;
  if (Al) Al[idx] = f2bf(v - bf2f(h));
}

__global__ void a_from_adj_k(const void* __restrict__ adj, const int* __restrict__ dtf,
                             long tot, u16* __restrict__ Ah) {
  int bf = *dtf;
  long idx = (long)blockIdx.x * 256 + threadIdx.x;
  if (idx >= tot) return;
  Ah[idx] = bf ? ((const u16*)adj)[idx] : f2bf(((const float*)adj)[idx]);
}

// build Ag (bf16) = src[perm,:] + I
__global__ void build_ag_bf_k(const void* __restrict__ src, int srcbf, int nsrc,
                              const int* __restrict__ perm, long tot, int ld,
                              u16* __restrict__ Ag, const int* __restrict__ dtf) {
  long idx = (long)blockIdx.x * 256 + threadIdx.x;
  if (idx >= tot) return;
  int r = (int)(idx / ld);
  int c = (int)(idx - (long)r * ld);
  int p = perm[r];
  float v = ld1(src, get_bf(srcbf, dtf), (long)p * nsrc + c);
  if (c == p) v += 1.f;
  Ag[idx] = f2bf(v);
}

__global__ void build_ag_f32_k(const float* __restrict__ src, int nsrc,
                               const int* __restrict__ perm, long tot, int ld,
                               float* __restrict__ Ag) {
  long idx = (long)blockIdx.x * 256 + threadIdx.x;
  if (idx >= tot) return;
  int r = (int)(idx / ld);
  int c = (int)(idx - (long)r * ld);
  int p = perm[r];
  float v = src[(long)p * nsrc + c];
  if (c == p) v += 1.f;
  Ag[idx] = v;
}

__global__ void transpose_k(const float* __restrict__ src, float* __restrict__ dst,
                            int rows, int cols) {
  __shared__ float tile[32][33];
  int bx = blockIdx.x * 32, by = blockIdx.y * 32;
  int x = bx + threadIdx.x;
  #pragma unroll
  for (int i = 0; i < 32; i += 8) {
    int y = by + threadIdx.y + i;
    if (x < cols && y < rows) tile[threadIdx.y + i][threadIdx.x] = src[(long)y * cols + x];
  }
  __syncthreads();
  x = by + threadIdx.x;
  #pragma unroll
  for (int i = 0; i < 32; i += 8) {
    int y = bx + threadIdx.y + i;
    if (x < rows && y < cols) dst[(long)y * rows + x] = tile[threadIdx.x][threadIdx.y + i];
  }
}

__global__ void zerodiag_k(float* __restrict__ A, int n) {
  int i = blockIdx.x * 256 + threadIdx.x;
  if (i < n) A[(long)i * n + i] = 0.f;
}

// ---------- fp32 GEMM, 128x128 tile (level-2 fused augment) ----------
__global__ __launch_bounds__(256) void gemm128_f32(
    const void* __restrict__ Ap, long lda, int abf,
    const void* __restrict__ Bp, long ldb, int bbf,
    float* __restrict__ C, long ldc, int M, int N, int K,
    const int* __restrict__ dtf)
{
  const int abf_ = get_bf(abf, dtf);
  const int bbf_ = get_bf(bbf, dtf);
  __shared__ float As[8][128];
  __shared__ float Bs[8][128];
  const int tid = threadIdx.x;
  const int tr = tid >> 4, tc = tid & 15;
  const long row0 = (long)blockIdx.y * 128;
  const long col0 = (long)blockIdx.x * 128;
  float acc[8][8];
  #pragma unroll
  for (int i = 0; i < 8; ++i)
    #pragma unroll
    for (int j = 0; j < 8; ++j) acc[i][j] = 0.f;

  const int am = tid >> 1;
  const int ak = (tid & 1) * 4;
  const int bk = tid >> 5;
  const int bn = (tid & 31) * 4;

  for (int k0 = 0; k0 < K; k0 += 8) {
    float va[4] = {0.f, 0.f, 0.f, 0.f};
    {
      long gm = row0 + am; long gk = k0 + ak;
      if (gm < M && gk < K) ld4(Ap, abf_, gm * lda + gk, gk, K, va);
    }
    As[ak + 0][am] = va[0]; As[ak + 1][am] = va[1];
    As[ak + 2][am] = va[2]; As[ak + 3][am] = va[3];

    float vb[4] = {0.f, 0.f, 0.f, 0.f};
    {
      long gk = k0 + bk; long gn = col0 + bn;
      if (gk < K && gn < N) ld4(Bp, bbf_, gk * ldb + gn, gn, N, vb);
    }
    Bs[bk][bn + 0] = vb[0]; Bs[bk][bn + 1] = vb[1];
    Bs[bk][bn + 2] = vb[2]; Bs[bk][bn + 3] = vb[3];

    __syncthreads();
    #pragma unroll
    for (int kk = 0; kk < 8; ++kk) {
      float a[8], b[8];
      #pragma unroll
      for (int i = 0; i < 8; ++i) a[i] = As[kk][tr * 8 + i];
      #pragma unroll
      for (int j = 0; j < 8; ++j) b[j] = Bs[kk][tc * 8 + j];
      #pragma unroll
      for (int i = 0; i < 8; ++i)
        #pragma unroll
        for (int j = 0; j < 8; ++j)
          acc[i][j] = fmaf(a[i], b[j], acc[i][j]);
    }
    __syncthreads();
  }
  #pragma unroll
  for (int i = 0; i < 8; ++i) {
    long gm = row0 + tr * 8 + i;
    if (gm >= M) continue;
    #pragma unroll
    for (int j = 0; j < 8; ++j) {
      long gn = col0 + tc * 8 + j;
      if (gn < N) C[gm * ldc + gn] = acc[i][j];
    }
  }
}

// ---------- fp64-accumulating GEMM, 64x64 tile (x@W feature path) ----------
__global__ __launch_bounds__(256) void gemm64_f64(
    const void* __restrict__ Ap, long lda, int abf,
    const void* __restrict__ Bp, long ldb, int bbf,
    float* __restrict__ C, long ldc, int M, int N, int K,
    const int* __restrict__ dtf)
{
  const int abf_ = get_bf(abf, dtf);
  const int bbf_ = get_bf(bbf, dtf);
  __shared__ float As[16][64];
  __shared__ float Bs[16][64];
  const int tid = threadIdx.x;
  const int tr = tid >> 4, tc = tid & 15;
  const long row0 = (long)blockIdx.y * 64;
  const long col0 = (long)blockIdx.x * 64;
  double acc[4][4];
  #pragma unroll
  for (int i = 0; i < 4; ++i)
    #pragma unroll
    for (int j = 0; j < 4; ++j) acc[i][j] = 0.0;

  const int am = tid >> 2;
  const int ak = (tid & 3) * 4;
  const int bk = tid >> 4;
  const int bn = (tid & 15) * 4;

  for (int k0 = 0; k0 < K; k0 += 16) {
    float va[4] = {0.f, 0.f, 0.f, 0.f};
    {
      long gm = row0 + am; long gk = k0 + ak;
      if (gm < M && gk < K) ld4(Ap, abf_, gm * lda + gk, gk, K, va);
    }
    As[ak + 0][am] = va[0]; As[ak + 1][am] = va[1];
    As[ak + 2][am] = va[2]; As[ak + 3][am] = va[3];

    float vb[4] = {0.f, 0.f, 0.f, 0.f};
    {
      long gk = k0 + bk; long gn = col0 + bn;
      if (gk < K && gn < N) ld4(Bp, bbf_, gk * ldb + gn, gn, N, vb);
    }
    Bs[bk][bn + 0] = vb[0]; Bs[bk][bn + 1] = vb[1];
    Bs[bk][bn + 2] = vb[2]; Bs[bk][bn + 3] = vb[3];

    __syncthreads();
    #pragma unroll
    for (int kk = 0; kk < 16; ++kk) {
      float a[4], b[4];
      #pragma unroll
      for (int i = 0; i < 4; ++i) a[i] = As[kk][tr * 4 + i];
      #pragma unroll
      for (int j = 0; j < 4; ++j) b[j] = Bs[kk][tc * 4 + j];
      #pragma unroll
      for (int i = 0; i < 4; ++i)
        #pragma unroll
        for (int j = 0; j < 4; ++j)
          acc[i][j] += (double)a[i] * (double)b[j];
    }
    __syncthreads();
  }
  #pragma unroll
  for (int i = 0; i < 4; ++i) {
    long gm = row0 + tr * 4 + i;
    if (gm >= M) continue;
    #pragma unroll
    for (int j = 0; j < 4; ++j) {
      long gn = col0 + tc * 4 + j;
      if (gn < N) C[gm * ldc + gn] = (float)acc[i][j];
    }
  }
}

// ---------- small kernels ----------
__global__ void upcast_k(const void* __restrict__ src, float* __restrict__ dst, int n,
                         const int* __restrict__ dtf) {
  int bf = *dtf;
  int i = blockIdx.x * 256 + threadIdx.x;
  if (i < n) dst[i] = ld1(src, bf, i);
}

__global__ void rowsum_dinv_k(const void* __restrict__ A, int abf, int n, float* __restrict__ dinv,
                              const int* __restrict__ dtf) {
  const int bf = get_bf(abf, dtf);
  const int row = blockIdx.x;
  const int tid = threadIdx.x;
  const long base = (long)row * n;
  double s = 0.0;
  for (int j = tid; j < n; j += 256) s += (double)ld1(A, bf, base + j);
  __shared__ double red[256];
  red[tid] = s; __syncthreads();
  for (int st = 128; st > 0; st >>= 1) {
    if (tid < st) red[tid] += red[tid + st];
    __syncthreads();
  }
  if (tid == 0) dinv[row] = (float)(1.0 / sqrt(red[0] + 2.0));
}

__global__ void scale_rows_k(float* __restrict__ Z, const float* __restrict__ dinv, int n, int h) {
  long idx = (long)blockIdx.x * 256 + threadIdx.x;
  if (idx < (long)n * h) Z[idx] *= dinv[idx / h];
}

// Y has leading dim 208; Zs has leading dim h(=200)
__global__ void gcn_epi_k(const float* __restrict__ Y, const float* __restrict__ Zs,
                          const float* __restrict__ dinv, const float* __restrict__ b,
                          float* __restrict__ out, int n, int h, int relu) {
  long idx = (long)blockIdx.x * 256 + threadIdx.x;
  if (idx >= (long)n * h) return;
  int i = (int)(idx / h);
  int j = (int)(idx - (long)i * h);
  float v = dinv[i] * (Y[(long)i * 208 + j] + 2.f * Zs[idx]) + b[j];
  if (relu) v = fmaxf(v, 0.f);
  out[idx] = v;
}

__global__ void pnorm_k(const float* __restrict__ p, int h, double* __restrict__ out) {
  int tid = threadIdx.x;
  double s = 0.0;
  for (int j = tid; j < h; j += 256) { double v = p[j]; s += v * v; }
  __shared__ double red[256];
  red[tid] = s; __syncthreads();
  for (int st = 128; st > 0; st >>= 1) {
    if (tid < st) red[tid] += red[tid + st];
    __syncthreads();
  }
  if (tid == 0) out[0] = sqrt(red[0]);
}

__global__ void score_k(const float* __restrict__ x, int h, const float* __restrict__ pw,
                        const double* __restrict__ pnorm, float* __restrict__ score) {
  int row = blockIdx.x, lane = threadIdx.x;
  const long base = (long)row * h;
  double s = 0.0;
  for (int j = lane; j < h; j += 64) s += (double)x[base + j] * (double)pw[j];
  for (int off = 32; off > 0; off >>= 1) s += __shfl_down(s, off);
  if (lane == 0) score[row] = (float)tanh(s / pnorm[0]);
}

// exact jax.lax.top_k order: descending value, ascending index on ties
__global__ __launch_bounds__(1024) void topk_k(const float* __restrict__ score,
                                               int n, int np2, int k, int* __restrict__ perm) {
  __shared__ u64 keys[4096];
  const int tid = threadIdx.x;
  for (int i = tid; i < np2; i += 1024) {
    u64 key = 0ULL;
    if (i < n) {
      u32 b = __float_as_uint(score[i]);
      u32 u = (b & 0x80000000u) ? ~b : (b | 0x80000000u);
      key = ((u64)u << 32) | (u32)(~(u32)i);
    }
    keys[i] = key;
  }
  __syncthreads();
  for (int size = 2; size <= np2; size <<= 1) {
    for (int stride = size >> 1; stride > 0; stride >>= 1) {
      for (int i = tid; i < np2; i += 1024) {
        int j = i ^ stride;
        if (j > i) {
          u64 a = keys[i], b = keys[j];
          bool up = ((i & size) == 0);
          if (up ? (a > b) : (a < b)) { keys[i] = b; keys[j] = a; }
        }
      }
      __syncthreads();
    }
  }
  for (int r = tid; r < k; r += 1024) {
    u64 kk = keys[np2 - 1 - r];
    perm[r] = (int)(~(u32)(kk & 0xFFFFFFFFull));
  }
}

__global__ void gatherx_k(const float* __restrict__ xsrc, const float* __restrict__ score,
                          const int* __restrict__ perm, int k, int h, float* __restrict__ xdst) {
  long idx = (long)blockIdx.x * 256 + threadIdx.x;
  if (idx >= (long)k * h) return;
  int r = (int)(idx / h);
  int c = (int)(idx - (long)r * h);
  int p = perm[r];
  xdst[idx] = xsrc[(long)p * h + c] * score[p];
}

__global__ void copy_k(const float* __restrict__ src, float* __restrict__ dst, long n) {
  long idx = (long)blockIdx.x * 256 + threadIdx.x;
  if (idx < n) dst[idx] = src[idx];
}

__global__ void scatter_add_k(float* __restrict__ dst, const int* __restrict__ perm,
                              const float* __restrict__ src, int k, int h) {
  long idx = (long)blockIdx.x * 256 + threadIdx.x;
  if (idx >= (long)k * h) return;
  int r = (int)(idx / h);
  int c = (int)(idx - (long)r * h);
  dst[(long)perm[r] * h + c] += src[idx];
}

__global__ void matvec2_k(const void* __restrict__ A, int abf, int n,
                          const float* __restrict__ Zs, float* __restrict__ Y,
                          const int* __restrict__ dtf) {
  const int bf = get_bf(abf, dtf);
  int row = blockIdx.x, tid = threadIdx.x;
  const long base = (long)row * n;
  double s0 = 0.0, s1 = 0.0;
  for (int j = tid; j < n; j += 256) {
    double a = (double)ld1(A, bf, base + j);
    s0 += a * (double)Zs[2 * j];
    s1 += a * (double)Zs[2 * j + 1];
  }
  __shared__ double r0[256], r1[256];
  r0[tid] = s0; r1[tid] = s1; __syncthreads();
  for (int st = 128; st > 0; st >>= 1) {
    if (tid < st) { r0[tid] += r0[tid + st]; r1[tid] += r1[tid + st]; }
    __syncthreads();
  }
  if (tid == 0) { Y[2 * row] = (float)r0[0]; Y[2 * row + 1] = (float)r1[0]; }
}

__global__ void final_k(const float* __restrict__ Y, const float* __restrict__ Zs,
                        const float* __restrict__ dinv, const float* __restrict__ b2,
                        int n, float* __restrict__ out) {
  int i = blockIdx.x * 256 + threadIdx.x;
  if (i >= n) return;
  double di = dinv[i];
  double t0 = di * ((double)Y[2 * i] + 2.0 * (double)Zs[2 * i]) + (double)b2[0];
  double t1 = di * ((double)Y[2 * i + 1] + 2.0 * (double)Zs[2 * i + 1]) + (double)b2[1];
  double m = fmax(t0, t1);
  double l = m + log(exp(t0 - m) + exp(t1 - m));
  out[2 * i] = (float)(t0 - l);
  out[2 * i + 1] = (float)(t1 - l);
}

// ---------- host orchestration ----------
extern "C" void kernel_launch(void* const* d_in, const int* in_sizes, int n_in,
                              void* d_out, int out_size, void* d_ws, size_t ws_size,
                              hipStream_t stream) {
  const int N0 = 4096, H = 200;
  const int K1 = 3072, K2 = 1536, K3 = 768;

  const void* in_x = d_in[0];
  const void* adj  = d_in[1];
  const void* w0 = d_in[2];  const void* b0 = d_in[3];
  const void* w1 = d_in[4];  const void* b1 = d_in[5];
  const void* w2 = d_in[6];  const void* b2 = d_in[7];
  const void* w3 = d_in[8];  const void* b3 = d_in[9];
  const void* p1 = d_in[10]; const void* p2 = d_in[11];
  const void* p3 = d_in[12];
  const void* u0w = d_in[13]; const void* u0b = d_in[14];
  const void* u1w = d_in[15]; const void* u1b = d_in[16];
  const void* u2w = d_in[17]; const void* u2b = d_in[18];

  char* wp = (char*)d_ws;
  auto alloc = [&](size_t bytes) -> void* {
    void* p = (void*)wp;
    wp += (bytes + 255) & ~(size_t)255;
    return p;
  };
  float* As1  = (float*)alloc((size_t)K1 * K1 * 4);          // 37.7 MB (fp32, for rowsum + next build)
  float* As2  = (float*)alloc((size_t)K2 * K2 * 4);          // 9.4 MB
  float* A3   = (float*)alloc((size_t)K3 * K3 * 4);          // 2.4 MB
  // shared scratch: Agb (syrk staging) / parts (agg k-split) / Ag3 buffers — lifetimes disjoint
  size_t scrBytes = (size_t)8 * N0 * 208 * 4;                // 27.3 MB (largest user: parts)
  void* scratchU = alloc(scrBytes);
  u16*   Agb  = (u16*)scratchU;
  float* parts = (float*)scratchU;
  float* Ag3f = (float*)scratchU;
  float* Ag3T = Ag3f + (size_t)K3 * K2;
  u16* Ah0 = (u16*)alloc((size_t)N0 * N0 * 2);               // 33.5 MB
  u16* Ah1 = (u16*)alloc((size_t)K1 * K1 * 2);               // 18.9 MB
  u16* Ah2 = (u16*)alloc((size_t)K2 * K2 * 2);               // 4.7 MB
  u16* Al2 = (u16*)alloc((size_t)K2 * K2 * 2);               // 4.7 MB
  u16* Ah3 = (u16*)alloc((size_t)K3 * K3 * 2);               // 1.2 MB
  u16* Al3 = (u16*)alloc((size_t)K3 * K3 * 2);               // 1.2 MB
  u16* ZT  = (u16*)alloc((size_t)3 * 208 * N0 * 2);          // 5.1 MB
  float* xs0  = (float*)alloc((size_t)N0 * H * 4);
  float* xs1  = (float*)alloc((size_t)K1 * H * 4);
  float* xs2  = (float*)alloc((size_t)K2 * H * 4);
  float* xcur = (float*)alloc((size_t)N0 * H * 4);
  float* xtmp = (float*)alloc((size_t)N0 * H * 4);
  float* Zbuf = (float*)alloc((size_t)N0 * H * 4);
  float* Ybuf = (float*)alloc((size_t)N0 * 208 * 4);
  float* Xinf = (float*)alloc((size_t)N0 * 3 * 4);
  float* dinv0 = (float*)alloc((size_t)N0 * 4);
  float* dinv1 = (float*)alloc((size_t)K1 * 4);
  float* dinv2 = (float*)alloc((size_t)K2 * 4);
  float* dinv3 = (float*)alloc((size_t)K3 * 4);
  float* scores = (float*)alloc((size_t)N0 * 4);
  int* perm1 = (int*)alloc((size_t)K1 * 4);
  int* perm2 = (int*)alloc((size_t)K2 * 4);
  int* perm3 = (int*)alloc((size_t)K3 * 4);
  double* pn = (double*)alloc(8);
  int* dtflag = (int*)alloc(256);
  float* w0f = (float*)alloc(3 * H * 4);  float* b0f = (float*)alloc(H * 4);
  float* w1f = (float*)alloc(H * H * 4);  float* b1f = (float*)alloc(H * 4);
  float* w2f = (float*)alloc(H * H * 4);  float* b2f = (float*)alloc(H * 4);
  float* w3f = (float*)alloc(H * H * 4);  float* b3f = (float*)alloc(H * 4);
  float* p1f = (float*)alloc(H * 4);
  float* p2f = (float*)alloc(H * 4);
  float* p3f = (float*)alloc(H * 4);
  float* u0wf = (float*)alloc(H * H * 4); float* u0bf = (float*)alloc(H * 4);
  float* u1wf = (float*)alloc(H * H * 4); float* u1bf = (float*)alloc(H * 4);
  float* u2wf = (float*)alloc(H * 2 * 4); float* u2bf = (float*)alloc(2 * 4);
  (void)in_sizes; (void)n_in; (void)out_size; (void)ws_size;

  detect_init_k<<<dim3(1), dim3(64), 0, stream>>>(dtflag);
  detect_k<<<dim3(4096), dim3(256), 0, stream>>>((const u32*)adj, (long)N0 * N0 / 2, dtflag);

  auto up = [&](const void* s, float* d, int n) {
    upcast_k<<<dim3((n + 255) / 256), dim3(256), 0, stream>>>(s, d, n, dtflag);
  };
  up(in_x, Xinf, N0 * 3);
  up(w0, w0f, 3 * H);  up(b0, b0f, H);
  up(w1, w1f, H * H);  up(b1, b1f, H);
  up(w2, w2f, H * H);  up(b2, b2f, H);
  up(w3, w3f, H * H);  up(b3, b3f, H);
  up(p1, p1f, H); up(p2, p2f, H); up(p3, p3f, H);
  up(u0w, u0wf, H * H); up(u0b, u0bf, H);
  up(u1w, u1wf, H * H); up(u1b, u1bf, H);
  up(u2w, u2wf, H * 2); up(u2b, u2bf, 2);

  // adj -> bf16 plane (exact {0,1})
  a_from_adj_k<<<dim3((unsigned)(((long)N0 * N0 + 255) / 256)), dim3(256), 0, stream>>>(
      adj, dtflag, (long)N0 * N0, Ah0);

  auto gemm64 = [&](const void* A, long lda, int abf, const void* B, long ldb, int bbf,
                    float* C, long ldc, int M, int Nn, int K) {
    dim3 g((Nn + 63) / 64, (M + 63) / 64);
    gemm64_f64<<<g, dim3(256), 0, stream>>>(A, lda, abf, B, ldb, bbf, C, ldc, M, Nn, K, dtflag);
  };

  // GCN with MFMA aggregation: out = maybe_relu(dinv .* (A@Zs + 2 Zs) + b)
  auto gcn = [&](const u16* Ah, const u16* Al, int n, const float* dinv, const float* Xin_,
                 int din, const float* W, const float* bb, float* out, int relu) {
    gemm64(Xin_, din, 0, W, H, 0, Zbuf, H, n, H, din);        // Z = Xin @ W (f64 acc)
    long tot = (long)n * H;
    scale_rows_k<<<dim3((unsigned)((tot + 255) / 256)), dim3(256), 0, stream>>>(Zbuf, dinv, n, H);
    zsplit_k<<<dim3(n / 32, 7), dim3(32, 8), 0, stream>>>(Zbuf, n, H, ZT);
    agg_mfma<13><<<dim3(n / 128, 8), dim3(256), 0, stream>>>(Ah, Al, ZT, parts, n, (n / 32) / 8);
    long n208 = (long)n * 208;
    reduce8_k<<<dim3((unsigned)((n208 + 255) / 256)), dim3(256), 0, stream>>>(parts, Ybuf, n208);
    gcn_epi_k<<<dim3((unsigned)((tot + 255) / 256)), dim3(256), 0, stream>>>(
        Ybuf, Zbuf, dinv, bb, out, n, H, relu);
  };

  auto pool = [&](const float* xin, int n, int np2, int k, const float* pwf,
                  int* perm, float* xout) {
    pnorm_k<<<dim3(1), dim3(256), 0, stream>>>(pwf, H, pn);
    score_k<<<dim3(n), dim3(64), 0, stream>>>(xin, H, pwf, pn, scores);
    topk_k<<<dim3(1), dim3(1024), 0, stream>>>(scores, n, np2, k, perm);
    long tot = (long)k * H;
    gatherx_k<<<dim3((unsigned)((tot + 255) / 256)), dim3(256), 0, stream>>>(
        xin, scores, perm, k, H, xout);
  };

  auto fused_aug_bf = [&](const void* src, int srcbf, int nsrc, const int* perm, int k,
                          float* dst) {
    long tot = (long)k * nsrc;
    build_ag_bf_k<<<dim3((unsigned)((tot + 255) / 256)), dim3(256), 0, stream>>>(
        src, srcbf, nsrc, perm, tot, nsrc, Agb, dtflag);
    dim3 g(k / 128, k / 128);
    syrk_bf16_mfma<<<g, dim3(256), 0, stream>>>(Agb, nsrc, dst, k, nsrc);
  };
  auto asplit = [&](const float* src, long tot, u16* Ah, u16* Al) {
    asplit_k<<<dim3((unsigned)((tot + 255) / 256)), dim3(256), 0, stream>>>(src, tot, Ah, Al);
  };

  // ---------------- forward ----------------
  rowsum_dinv_k<<<dim3(N0), dim3(256), 0, stream>>>(adj, -1, N0, dinv0, dtflag);
  gcn(Ah0, nullptr, N0, dinv0, Xinf, 3, w0f, b0f, xs0, 1);    // xs0 = relu(gcn0)

  // down 0
  pool(xs0, N0, 4096, K1, p1f, perm1, xcur);
  fused_aug_bf(adj, -1, N0, perm1, K1, As1);                  // As1 (exact ints)
  asplit(As1, (long)K1 * K1, Ah1, nullptr);                   // ints <= ~70: hi plane exact
  rowsum_dinv_k<<<dim3(K1), dim3(256), 0, stream>>>(As1, 0, K1, dinv1, dtflag);
  gcn(Ah1, nullptr, K1, dinv1, xcur, H, w1f, b1f, xs1, 1);

  // down 1
  pool(xs1, K1, 4096, K2, p2f, perm2, xcur);
  fused_aug_bf(As1, 0, K1, perm2, K2, As2);                   // As2 (exact ints, may exceed 256)
  asplit(As2, (long)K2 * K2, Ah2, Al2);                       // exact hi+lo split
  rowsum_dinv_k<<<dim3(K2), dim3(256), 0, stream>>>(As2, 0, K2, dinv2, dtflag);
  gcn(Ah2, Al2, K2, dinv2, xcur, H, w2f, b2f, xs2, 1);

  // down 2 (fp32 product; values large, no further top-k depends on it)
  pool(xs2, K2, 2048, K3, p3f, perm3, xcur);
  {
    long tot = (long)K3 * K2;
    build_ag_f32_k<<<dim3((unsigned)((tot + 255) / 256)), dim3(256), 0, stream>>>(
        As2, K2, perm3, tot, K2, Ag3f);
    transpose_k<<<dim3(K2 / 32, K3 / 32), dim3(32, 8), 0, stream>>>(Ag3f, Ag3T, K3, K2);
    gemm128_f32<<<dim3(K3 / 128, K3 / 128), dim3(256), 0, stream>>>(
        Ag3f, K2, 0, Ag3T, K3, 0, A3, K3, K3, K3, K2, dtflag);
    zerodiag_k<<<dim3((K3 + 255) / 256), dim3(256), 0, stream>>>(A3, K3);
  }
  asplit(A3, (long)K3 * K3, Ah3, Al3);
  rowsum_dinv_k<<<dim3(K3), dim3(256), 0, stream>>>(A3, 0, K3, dinv3, dtflag);
  gcn(Ah3, Al3, K3, dinv3, xcur, H, w3f, b3f, xcur, 1);       // x (768xH)

  // up 0: j=2
  copy_k<<<dim3((unsigned)(((long)K2 * H + 255) / 256)), dim3(256), 0, stream>>>(xs2, xtmp, (long)K2 * H);
  scatter_add_k<<<dim3((unsigned)(((long)K3 * H + 255) / 256)), dim3(256), 0, stream>>>(xtmp, perm3, xcur, K3, H);
  gcn(Ah2, Al2, K2, dinv2, xtmp, H, u0wf, u0bf, xcur, 1);

  // up 1: j=1
  copy_k<<<dim3((unsigned)(((long)K1 * H + 255) / 256)), dim3(256), 0, stream>>>(xs1, xtmp, (long)K1 * H);
  scatter_add_k<<<dim3((unsigned)(((long)K2 * H + 255) / 256)), dim3(256), 0, stream>>>(xtmp, perm2, xcur, K2, H);
  gcn(Ah1, nullptr, K1, dinv1, xtmp, H, u1wf, u1bf, xcur, 1);

  // up 2: j=0 (final GCN, 2 output cols, then log_softmax)
  copy_k<<<dim3((unsigned)(((long)N0 * H + 255) / 256)), dim3(256), 0, stream>>>(xs0, xtmp, (long)N0 * H);
  scatter_add_k<<<dim3((unsigned)(((long)K1 * H + 255) / 256)), dim3(256), 0, stream>>>(xtmp, perm1, xcur, K1, H);
  gemm64(xtmp, H, 0, u2wf, 2, 0, Zbuf, 2, N0, 2, H);
  scale_rows_k<<<dim3((N0 * 2 + 255) / 256), dim3(256), 0, stream>>>(Zbuf, dinv0, N0, 2);
  matvec2_k<<<dim3(N0), dim3(256), 0, stream>>>(adj, -1, N0, Zbuf, Ybuf, dtflag);
  final_k<<<dim3((N0 + 255) / 256), dim3(256), 0, stream>>>(Ybuf, Zbuf, dinv0, u2bf, N0, (float*)d_out);
}

// Round 5
// 1114.900 us; speedup vs baseline: 4.2677x; 1.2528x over previous
//
#include <hip/hip_runtime.h>

typedef unsigned short u16;
typedef unsigned int u32;
typedef unsigned long long u64;
typedef __attribute__((ext_vector_type(8))) short bfrag8;
typedef __attribute__((ext_vector_type(4))) float f32x4;
typedef __attribute__((address_space(1))) const void gconst_void;
typedef __attribute__((address_space(3))) void lds_void_t;

// ---------- helpers ----------
__device__ __forceinline__ float bf2f(u16 u) {
  return __uint_as_float(((u32)u) << 16);
}
__device__ __forceinline__ u16 f2bf(float f) {
  u32 u = __float_as_uint(f);
  u32 r = (u + 0x7FFFu + ((u >> 16) & 1u)) >> 16;  // RTNE
  return (u16)r;
}
__device__ __forceinline__ float ld1(const void* p, int isbf, long idx) {
  return isbf ? bf2f(((const u16*)p)[idx]) : ((const float*)p)[idx];
}
__device__ __forceinline__ void ld4(const void* p, int isbf, long base, long gc, long bound, float v[4]) {
  if (gc + 3 < bound && ((base & 3) == 0)) {
    if (isbf) {
      const ushort4 u = *(const ushort4*)((const u16*)p + base);
      v[0] = bf2f(u.x); v[1] = bf2f(u.y); v[2] = bf2f(u.z); v[3] = bf2f(u.w);
    } else {
      const float4 f = *(const float4*)((const float*)p + base);
      v[0] = f.x; v[1] = f.y; v[2] = f.z; v[3] = f.w;
    }
  } else {
    #pragma unroll
    for (int d = 0; d < 4; ++d) v[d] = (gc + d < bound) ? ld1(p, isbf, base + d) : 0.f;
  }
}

// ---------- input dtype autodetect (bf16 vs f32) ----------
__global__ void detect_init_k(int* flag) { if (threadIdx.x == 0 && blockIdx.x == 0) *flag = 0; }

__global__ void detect_k(const u32* __restrict__ a, long nw, int* __restrict__ flag) {
  long stride = (long)gridDim.x * 256;
  int f = 0;
  for (long j = (long)blockIdx.x * 256 + threadIdx.x; j < nw; j += stride) {
    u32 w = a[j];
    if (w == 0x00003F80u || w == 0x3F803F80u) f = 1;
  }
  if (__any(f)) {
    if ((threadIdx.x & 63) == 0) atomicOr(flag, 1);
  }
}

__device__ __forceinline__ int get_bf(int abf, const int* dtf) {
  return (abf >= 0) ? abf : *dtf;
}

// ---------- async global->LDS stage: 64 lanes x 16B ----------
__device__ __forceinline__ void stage16(const u16* g, u16* ldsbase, int lane) {
#if __has_builtin(__builtin_amdgcn_global_load_lds)
  __builtin_amdgcn_global_load_lds((gconst_void*)g, (lds_void_t*)ldsbase, 16, 0, 0);
#else
  *(ushort4*)(ldsbase + lane * 8) = *(const ushort4*)g;
#endif
}

// ---------- triangle MFMA SYRK: C = Ag @ Ag^T, zero diag, mirror-write ----------
// grid: nt(nt+1)/2 blocks (nt = M/128); exact for integer Ag entries <= 256, sums < 2^24
__global__ __launch_bounds__(256) void syrk_tri_bf16(
    const u16* __restrict__ Ag, int ldk, float* __restrict__ C, int ldc, int K)
{
  __shared__ u16 At[128 * 32];
  __shared__ u16 Bt[128 * 32];
  __shared__ float tb[4][16][17];
  const int t = blockIdx.x;
  int ti = (int)((sqrtf((float)(8 * t + 1)) - 1.0f) * 0.5f);
  while ((ti + 1) * (ti + 2) / 2 <= t) ++ti;
  while (ti * (ti + 1) / 2 > t) --ti;
  const int tj = t - ti * (ti + 1) / 2;

  const int tid = threadIdx.x;
  const int wave = tid >> 6, lane = tid & 63;
  const int wr = wave >> 1, wc = wave & 1;
  const long rowA0 = (long)ti * 128;
  const long rowB0 = (long)tj * 128;

  f32x4 acc[4][4];
  #pragma unroll
  for (int i = 0; i < 4; ++i)
    #pragma unroll
    for (int j = 0; j < 4; ++j) acc[i][j] = (f32x4)0.f;

  const int srow = (lane >> 2);
  const int scol = (lane & 3) * 8;
  const int m = lane & 15, q = lane >> 4;

  for (int k0 = 0; k0 < K; k0 += 32) {
    #pragma unroll
    for (int tt = 0; tt < 2; ++tt) {
      const int r = wave * 32 + tt * 16;
      stage16(Ag + (rowA0 + r + srow) * (long)ldk + k0 + scol, At + r * 32, lane);
      stage16(Ag + (rowB0 + r + srow) * (long)ldk + k0 + scol, Bt + r * 32, lane);
    }
    __syncthreads();

    bfrag8 af[4], bf[4];
    #pragma unroll
    for (int mt = 0; mt < 4; ++mt)
      af[mt] = *(const bfrag8*)(At + (wr * 64 + mt * 16 + m) * 32 + q * 8);
    #pragma unroll
    for (int nt = 0; nt < 4; ++nt)
      bf[nt] = *(const bfrag8*)(Bt + (wc * 64 + nt * 16 + m) * 32 + q * 8);
    #pragma unroll
    for (int mt = 0; mt < 4; ++mt)
      #pragma unroll
      for (int nt = 0; nt < 4; ++nt)
        acc[mt][nt] = __builtin_amdgcn_mfma_f32_16x16x32_bf16(af[mt], bf[nt], acc[mt][nt], 0, 0, 0);
    __syncthreads();
  }

  // normal write (lower-triangle tile), diag zero
  #pragma unroll
  for (int mt = 0; mt < 4; ++mt) {
    #pragma unroll
    for (int nt = 0; nt < 4; ++nt) {
      const long gr0 = rowA0 + wr * 64 + mt * 16 + q * 4;
      const long gc = rowB0 + wc * 64 + nt * 16 + m;
      #pragma unroll
      for (int r = 0; r < 4; ++r) {
        const long gr = gr0 + r;
        C[gr * ldc + gc] = (gr == gc) ? 0.f : acc[mt][nt][r];
      }
    }
  }
  // mirror write via in-LDS 16x16 fragment transpose (coalesced)
  if (ti != tj) {
    #pragma unroll
    for (int mt = 0; mt < 4; ++mt) {
      #pragma unroll
      for (int nt = 0; nt < 4; ++nt) {
        #pragma unroll
        for (int r = 0; r < 4; ++r) tb[wave][q * 4 + r][m] = acc[mt][nt][r];
        const long baseR = rowB0 + wc * 64 + nt * 16;  // mirror rows
        const long baseC = rowA0 + wr * 64 + mt * 16;  // mirror cols
        #pragma unroll
        for (int r = 0; r < 4; ++r)
          C[(baseR + q * 4 + r) * ldc + baseC + m] = tb[wave][m][q * 4 + r];
      }
    }
  }
}

// ---------- 2-plane K-split SYRK (level-2 augment): parts[z] = tiles of (Ah+Al)(Ah+Al)^T ----------
__global__ __launch_bounds__(256) void syrk2_ks(
    const u16* __restrict__ Ah, const u16* __restrict__ Al, int ldk,
    float* __restrict__ parts, int n, int per)
{
  __shared__ u16 Ath[128 * 32];
  __shared__ u16 Atl[128 * 32];
  __shared__ u16 Bth[128 * 32];
  __shared__ u16 Btl[128 * 32];
  const int tid = threadIdx.x;
  const int wave = tid >> 6, lane = tid & 63;
  const int wr = wave >> 1, wc = wave & 1;
  const long rowA0 = (long)blockIdx.y * 128;
  const long rowB0 = (long)blockIdx.x * 128;
  const int kbeg = blockIdx.z * per;
  const int kend = kbeg + per;

  f32x4 acc[4][4];
  #pragma unroll
  for (int i = 0; i < 4; ++i)
    #pragma unroll
    for (int j = 0; j < 4; ++j) acc[i][j] = (f32x4)0.f;

  const int srow = (lane >> 2);
  const int scol = (lane & 3) * 8;
  const int m = lane & 15, q = lane >> 4;

  for (int k0 = kbeg; k0 < kend; k0 += 32) {
    #pragma unroll
    for (int tt = 0; tt < 2; ++tt) {
      const int r = wave * 32 + tt * 16;
      stage16(Ah + (rowA0 + r + srow) * (long)ldk + k0 + scol, Ath + r * 32, lane);
      stage16(Al + (rowA0 + r + srow) * (long)ldk + k0 + scol, Atl + r * 32, lane);
      stage16(Ah + (rowB0 + r + srow) * (long)ldk + k0 + scol, Bth + r * 32, lane);
      stage16(Al + (rowB0 + r + srow) * (long)ldk + k0 + scol, Btl + r * 32, lane);
    }
    __syncthreads();

    bfrag8 afh[4], afl[4], bfh[4], bfl[4];
    #pragma unroll
    for (int mt = 0; mt < 4; ++mt) {
      afh[mt] = *(const bfrag8*)(Ath + (wr * 64 + mt * 16 + m) * 32 + q * 8);
      afl[mt] = *(const bfrag8*)(Atl + (wr * 64 + mt * 16 + m) * 32 + q * 8);
    }
    #pragma unroll
    for (int nt = 0; nt < 4; ++nt) {
      bfh[nt] = *(const bfrag8*)(Bth + (wc * 64 + nt * 16 + m) * 32 + q * 8);
      bfl[nt] = *(const bfrag8*)(Btl + (wc * 64 + nt * 16 + m) * 32 + q * 8);
    }
    #pragma unroll
    for (int mt = 0; mt < 4; ++mt)
      #pragma unroll
      for (int nt = 0; nt < 4; ++nt) {
        acc[mt][nt] = __builtin_amdgcn_mfma_f32_16x16x32_bf16(afh[mt], bfh[nt], acc[mt][nt], 0, 0, 0);
        acc[mt][nt] = __builtin_amdgcn_mfma_f32_16x16x32_bf16(afh[mt], bfl[nt], acc[mt][nt], 0, 0, 0);
        acc[mt][nt] = __builtin_amdgcn_mfma_f32_16x16x32_bf16(afl[mt], bfh[nt], acc[mt][nt], 0, 0, 0);
        acc[mt][nt] = __builtin_amdgcn_mfma_f32_16x16x32_bf16(afl[mt], bfl[nt], acc[mt][nt], 0, 0, 0);
      }
    __syncthreads();
  }

  float* P = parts + (long)blockIdx.z * n * n;
  #pragma unroll
  for (int mt = 0; mt < 4; ++mt) {
    #pragma unroll
    for (int nt = 0; nt < 4; ++nt) {
      const long gr0 = rowA0 + wr * 64 + mt * 16 + q * 4;
      const long gc = rowB0 + wc * 64 + nt * 16 + m;
      #pragma unroll
      for (int r = 0; r < 4; ++r)
        P[(gr0 + r) * n + gc] = acc[mt][nt][r];
    }
  }
}

// reduce nz parts of an n x n matrix, zero diag
__global__ void reduce_sq_k(const float* __restrict__ parts, float* __restrict__ Y,
                            int n, int nz) {
  long idx = (long)blockIdx.x * 256 + threadIdx.x;
  long nn = (long)n * n;
  if (idx >= nn) return;
  float s = 0.f;
  for (int c = 0; c < nz; ++c) s += parts[(long)c * nn + idx];
  long row = idx / n, col = idx - row * n;
  Y[idx] = (row == col) ? 0.f : s;
}

// build level-2 augment operand in exact 2-plane bf16: v = As2[perm_r, c] + (c==perm_r)
__global__ void build_ag3_split_k(const float* __restrict__ src, int nsrc,
                                  const int* __restrict__ perm, long tot, int ld,
                                  u16* __restrict__ Agh, u16* __restrict__ Agl) {
  long idx = (long)blockIdx.x * 256 + threadIdx.x;
  if (idx >= tot) return;
  int r = (int)(idx / ld);
  int c = (int)(idx - (long)r * ld);
  int p = perm[r];
  float v = src[(long)p * nsrc + c];
  if (c == p) v += 1.f;
  u16 h = f2bf(v);
  Agh[idx] = h;
  Agl[idx] = f2bf(v - bf2f(h));
}

// ---------- MFMA aggregation: Y = A @ Z (A exact bf16 planes, Z 3-plane split) ----------
template<int NT>
__global__ __launch_bounds__(256) void agg_mfma(
    const u16* __restrict__ Ah, const u16* __restrict__ Al,
    const u16* __restrict__ ZT, float* __restrict__ parts,
    int K, int per_steps)
{
  __shared__ u16 At[128 * 32];
  __shared__ u16 Alt[128 * 32];
  __shared__ u16 Zt[3 * NT * 512];
  const int tid = threadIdx.x;
  const int wave = tid >> 6, lane = tid & 63;
  const long row0 = (long)blockIdx.x * 128;
  const int chunk = blockIdx.y;
  const int kbeg = chunk * per_steps * 32;
  const int kend = min(K, kbeg + per_steps * 32);
  const int m = lane & 15, q = lane >> 4;
  const int srow = lane >> 2, scol = (lane & 3) * 8;
  const bool hasAl = (Al != nullptr);

  f32x4 acc[2][NT];
  #pragma unroll
  for (int rt = 0; rt < 2; ++rt)
    #pragma unroll
    for (int ct = 0; ct < NT; ++ct) acc[rt][ct] = (f32x4)0.f;

  for (int k0 = kbeg; k0 < kend; k0 += 32) {
    #pragma unroll
    for (int t = 0; t < 2; ++t) {
      const int r = wave * 32 + t * 16;
      stage16(Ah + (row0 + r + srow) * (long)K + k0 + scol, At + r * 32, lane);
      if (hasAl)
        stage16(Al + (row0 + r + srow) * (long)K + k0 + scol, Alt + r * 32, lane);
    }
    for (int s = wave; s < 3 * NT; s += 4) {
      const u16* g = ZT + ((long)(s * 16 + srow)) * K + k0 + scol;
      stage16(g, Zt + s * 512, lane);
    }
    __syncthreads();

    bfrag8 af0 = *(const bfrag8*)(At + (wave * 32 + m) * 32 + q * 8);
    bfrag8 af1 = *(const bfrag8*)(At + (wave * 32 + 16 + m) * 32 + q * 8);
    bfrag8 al0, al1;
    if (hasAl) {
      al0 = *(const bfrag8*)(Alt + (wave * 32 + m) * 32 + q * 8);
      al1 = *(const bfrag8*)(Alt + (wave * 32 + 16 + m) * 32 + q * 8);
    }
    #pragma unroll
    for (int ct = 0; ct < NT; ++ct) {
      bfrag8 b0 = *(const bfrag8*)(Zt + (0 * NT + ct) * 512 + m * 32 + q * 8);
      bfrag8 b1 = *(const bfrag8*)(Zt + (1 * NT + ct) * 512 + m * 32 + q * 8);
      bfrag8 b2 = *(const bfrag8*)(Zt + (2 * NT + ct) * 512 + m * 32 + q * 8);
      acc[0][ct] = __builtin_amdgcn_mfma_f32_16x16x32_bf16(af0, b0, acc[0][ct], 0, 0, 0);
      acc[0][ct] = __builtin_amdgcn_mfma_f32_16x16x32_bf16(af0, b1, acc[0][ct], 0, 0, 0);
      acc[0][ct] = __builtin_amdgcn_mfma_f32_16x16x32_bf16(af0, b2, acc[0][ct], 0, 0, 0);
      acc[1][ct] = __builtin_amdgcn_mfma_f32_16x16x32_bf16(af1, b0, acc[1][ct], 0, 0, 0);
      acc[1][ct] = __builtin_amdgcn_mfma_f32_16x16x32_bf16(af1, b1, acc[1][ct], 0, 0, 0);
      acc[1][ct] = __builtin_amdgcn_mfma_f32_16x16x32_bf16(af1, b2, acc[1][ct], 0, 0, 0);
      if (hasAl) {
        acc[0][ct] = __builtin_amdgcn_mfma_f32_16x16x32_bf16(al0, b0, acc[0][ct], 0, 0, 0);
        acc[0][ct] = __builtin_amdgcn_mfma_f32_16x16x32_bf16(al0, b1, acc[0][ct], 0, 0, 0);
        acc[1][ct] = __builtin_amdgcn_mfma_f32_16x16x32_bf16(al1, b0, acc[1][ct], 0, 0, 0);
        acc[1][ct] = __builtin_amdgcn_mfma_f32_16x16x32_bf16(al1, b1, acc[1][ct], 0, 0, 0);
      }
    }
    __syncthreads();
  }

  float* P = parts + (long)chunk * gridDim.x * 128 * (NT * 16);
  #pragma unroll
  for (int rt = 0; rt < 2; ++rt) {
    #pragma unroll
    for (int ct = 0; ct < NT; ++ct) {
      const long grow0 = row0 + wave * 32 + rt * 16 + q * 4;
      const long gcol = ct * 16 + m;
      #pragma unroll
      for (int r = 0; r < 4; ++r)
        P[(grow0 + r) * (NT * 16) + gcol] = acc[rt][ct][r];
    }
  }
}

__global__ void reduce8_k(const float* __restrict__ parts, float* __restrict__ Y, long n208) {
  long idx = (long)blockIdx.x * 256 + threadIdx.x;
  if (idx >= n208) return;
  float s = 0.f;
  #pragma unroll
  for (int c = 0; c < 8; ++c) s += parts[(long)c * n208 + idx];
  Y[idx] = s;
}

// Z (n x 200 f32) -> 3 bf16 planes transposed: ZT[(p*208+c)*n + k]
__global__ void zsplit_k(const float* __restrict__ Z, int n, int h, u16* __restrict__ ZT) {
  __shared__ float t[32][33];
  const int kb = blockIdx.x * 32;
  const int cb = blockIdx.y * 32;
  #pragma unroll
  for (int i = 0; i < 32; i += 8) {
    int k = kb + threadIdx.y + i;
    int c = cb + threadIdx.x;
    t[threadIdx.y + i][threadIdx.x] = (c < h) ? Z[(long)k * h + c] : 0.f;
  }
  __syncthreads();
  #pragma unroll
  for (int i = 0; i < 32; i += 8) {
    int c = cb + threadIdx.y + i;
    if (c >= 208) continue;
    long k = kb + threadIdx.x;
    float v = t[threadIdx.x][threadIdx.y + i];
    u16 hi = f2bf(v); float r1 = v - bf2f(hi);
    u16 mi = f2bf(r1); float r2 = r1 - bf2f(mi);
    u16 lo = f2bf(r2);
    ZT[((long)0 * 208 + c) * n + k] = hi;
    ZT[((long)1 * 208 + c) * n + k] = mi;
    ZT[((long)2 * 208 + c) * n + k] = lo;
  }
}

// split fp32 A into exact bf16 hi/lo planes (Al nullable)
__global__ void asplit_k(const float* __restrict__ src, long tot,
                         u16* __restrict__ Ah, u16* __restrict__ Al) {
  long idx = (long)blockIdx.x * 256 + threadIdx.x;
  if (idx >= tot) return;
  float v = src[idx];
  u16 h = f2bf(v);
  Ah[idx] = h;
  if (Al) Al[idx] = f2bf(v - bf2f(h));
}

__global__ void a_from_adj_k(const void* __restrict__ adj, const int* __restrict__ dtf,
                             long tot, u16* __restrict__ Ah) {
  int bf = *dtf;
  long idx = (long)blockIdx.x * 256 + threadIdx.x;
  if (idx >= tot) return;
  Ah[idx] = bf ? ((const u16*)adj)[idx] : f2bf(((const float*)adj)[idx]);
}

// build Ag (bf16) = src[perm,:] + I
__global__ void build_ag_bf_k(const void* __restrict__ src, int srcbf, int nsrc,
                              const int* __restrict__ perm, long tot, int ld,
                              u16* __restrict__ Ag, const int* __restrict__ dtf) {
  long idx = (long)blockIdx.x * 256 + threadIdx.x;
  if (idx >= tot) return;
  int r = (int)(idx / ld);
  int c = (int)(idx - (long)r * ld);
  int p = perm[r];
  float v = ld1(src, get_bf(srcbf, dtf), (long)p * nsrc + c);
  if (c == p) v += 1.f;
  Ag[idx] = f2bf(v);
}

// ---------- fp64-accumulating GEMM, 64x64 tile (x@W feature path) ----------
__global__ __launch_bounds__(256) void gemm64_f64(
    const void* __restrict__ Ap, long lda, int abf,
    const void* __restrict__ Bp, long ldb, int bbf,
    float* __restrict__ C, long ldc, int M, int N, int K,
    const int* __restrict__ dtf)
{
  const int abf_ = get_bf(abf, dtf);
  const int bbf_ = get_bf(bbf, dtf);
  __shared__ float As[16][64];
  __shared__ float Bs[16][64];
  const int tid = threadIdx.x;
  const int tr = tid >> 4, tc = tid & 15;
  const long row0 = (long)blockIdx.y * 64;
  const long col0 = (long)blockIdx.x * 64;
  double acc[4][4];
  #pragma unroll
  for (int i = 0; i < 4; ++i)
    #pragma unroll
    for (int j = 0; j < 4; ++j) acc[i][j] = 0.0;

  const int am = tid >> 2;
  const int ak = (tid & 3) * 4;
  const int bk = tid >> 4;
  const int bn = (tid & 15) * 4;

  for (int k0 = 0; k0 < K; k0 += 16) {
    float va[4] = {0.f, 0.f, 0.f, 0.f};
    {
      long gm = row0 + am; long gk = k0 + ak;
      if (gm < M && gk < K) ld4(Ap, abf_, gm * lda + gk, gk, K, va);
    }
    As[ak + 0][am] = va[0]; As[ak + 1][am] = va[1];
    As[ak + 2][am] = va[2]; As[ak + 3][am] = va[3];

    float vb[4] = {0.f, 0.f, 0.f, 0.f};
    {
      long gk = k0 + bk; long gn = col0 + bn;
      if (gk < K && gn < N) ld4(Bp, bbf_, gk * ldb + gn, gn, N, vb);
    }
    Bs[bk][bn + 0] = vb[0]; Bs[bk][bn + 1] = vb[1];
    Bs[bk][bn + 2] = vb[2]; Bs[bk][bn + 3] = vb[3];

    __syncthreads();
    #pragma unroll
    for (int kk = 0; kk < 16; ++kk) {
      float a[4], b[4];
      #pragma unroll
      for (int i = 0; i < 4; ++i) a[i] = As[kk][tr * 4 + i];
      #pragma unroll
      for (int j = 0; j < 4; ++j) b[j] = Bs[kk][tc * 4 + j];
      #pragma unroll
      for (int i = 0; i < 4; ++i)
        #pragma unroll
        for (int j = 0; j < 4; ++j)
          acc[i][j] += (double)a[i] * (double)b[j];
    }
    __syncthreads();
  }
  #pragma unroll
  for (int i = 0; i < 4; ++i) {
    long gm = row0 + tr * 4 + i;
    if (gm >= M) continue;
    #pragma unroll
    for (int j = 0; j < 4; ++j) {
      long gn = col0 + tc * 4 + j;
      if (gn < N) C[gm * ldc + gn] = (float)acc[i][j];
    }
  }
}

// ---------- small kernels ----------
__global__ void upcast_k(const void* __restrict__ src, float* __restrict__ dst, int n,
                         const int* __restrict__ dtf) {
  int bf = *dtf;
  int i = blockIdx.x * 256 + threadIdx.x;
  if (i < n) dst[i] = ld1(src, bf, i);
}

__global__ void rowsum_dinv_k(const void* __restrict__ A, int abf, int n, float* __restrict__ dinv,
                              const int* __restrict__ dtf) {
  const int bf = get_bf(abf, dtf);
  const int row = blockIdx.x;
  const int tid = threadIdx.x;
  const long base = (long)row * n;
  double s = 0.0;
  for (int j = tid; j < n; j += 256) s += (double)ld1(A, bf, base + j);
  __shared__ double red[256];
  red[tid] = s; __syncthreads();
  for (int st = 128; st > 0; st >>= 1) {
    if (tid < st) red[tid] += red[tid + st];
    __syncthreads();
  }
  if (tid == 0) dinv[row] = (float)(1.0 / sqrt(red[0] + 2.0));
}

__global__ void scale_rows_k(float* __restrict__ Z, const float* __restrict__ dinv, int n, int h) {
  long idx = (long)blockIdx.x * 256 + threadIdx.x;
  if (idx < (long)n * h) Z[idx] *= dinv[idx / h];
}

// Y has leading dim 208; Zs has leading dim h(=200)
__global__ void gcn_epi_k(const float* __restrict__ Y, const float* __restrict__ Zs,
                          const float* __restrict__ dinv, const float* __restrict__ b,
                          float* __restrict__ out, int n, int h, int relu) {
  long idx = (long)blockIdx.x * 256 + threadIdx.x;
  if (idx >= (long)n * h) return;
  int i = (int)(idx / h);
  int j = (int)(idx - (long)i * h);
  float v = dinv[i] * (Y[(long)i * 208 + j] + 2.f * Zs[idx]) + b[j];
  if (relu) v = fmaxf(v, 0.f);
  out[idx] = v;
}

__global__ void pnorm_k(const float* __restrict__ p, int h, double* __restrict__ out) {
  int tid = threadIdx.x;
  double s = 0.0;
  for (int j = tid; j < h; j += 256) { double v = p[j]; s += v * v; }
  __shared__ double red[256];
  red[tid] = s; __syncthreads();
  for (int st = 128; st > 0; st >>= 1) {
    if (tid < st) red[tid] += red[tid + st];
    __syncthreads();
  }
  if (tid == 0) out[0] = sqrt(red[0]);
}

__global__ void score_k(const float* __restrict__ x, int h, const float* __restrict__ pw,
                        const double* __restrict__ pnorm, float* __restrict__ score) {
  int row = blockIdx.x, lane = threadIdx.x;
  const long base = (long)row * h;
  double s = 0.0;
  for (int j = lane; j < h; j += 64) s += (double)x[base + j] * (double)pw[j];
  for (int off = 32; off > 0; off >>= 1) s += __shfl_down(s, off);
  if (lane == 0) score[row] = (float)tanh(s / pnorm[0]);
}

// exact jax.lax.top_k order: descending value, ascending index on ties
__global__ __launch_bounds__(1024) void topk_k(const float* __restrict__ score,
                                               int n, int np2, int k, int* __restrict__ perm) {
  __shared__ u64 keys[4096];
  const int tid = threadIdx.x;
  for (int i = tid; i < np2; i += 1024) {
    u64 key = 0ULL;
    if (i < n) {
      u32 b = __float_as_uint(score[i]);
      u32 u = (b & 0x80000000u) ? ~b : (b | 0x80000000u);
      key = ((u64)u << 32) | (u32)(~(u32)i);
    }
    keys[i] = key;
  }
  __syncthreads();
  for (int size = 2; size <= np2; size <<= 1) {
    for (int stride = size >> 1; stride > 0; stride >>= 1) {
      for (int i = tid; i < np2; i += 1024) {
        int j = i ^ stride;
        if (j > i) {
          u64 a = keys[i], b = keys[j];
          bool up = ((i & size) == 0);
          if (up ? (a > b) : (a < b)) { keys[i] = b; keys[j] = a; }
        }
      }
      __syncthreads();
    }
  }
  for (int r = tid; r < k; r += 1024) {
    u64 kk = keys[np2 - 1 - r];
    perm[r] = (int)(~(u32)(kk & 0xFFFFFFFFull));
  }
}

__global__ void gatherx_k(const float* __restrict__ xsrc, const float* __restrict__ score,
                          const int* __restrict__ perm, int k, int h, float* __restrict__ xdst) {
  long idx = (long)blockIdx.x * 256 + threadIdx.x;
  if (idx >= (long)k * h) return;
  int r = (int)(idx / h);
  int c = (int)(idx - (long)r * h);
  int p = perm[r];
  xdst[idx] = xsrc[(long)p * h + c] * score[p];
}

__global__ void copy_k(const float* __restrict__ src, float* __restrict__ dst, long n) {
  long idx = (long)blockIdx.x * 256 + threadIdx.x;
  if (idx < n) dst[idx] = src[idx];
}

__global__ void scatter_add_k(float* __restrict__ dst, const int* __restrict__ perm,
                              const float* __restrict__ src, int k, int h) {
  long idx = (long)blockIdx.x * 256 + threadIdx.x;
  if (idx >= (long)k * h) return;
  int r = (int)(idx / h);
  int c = (int)(idx - (long)r * h);
  dst[(long)perm[r] * h + c] += src[idx];
}

__global__ void matvec2_k(const void* __restrict__ A, int abf, int n,
                          const float* __restrict__ Zs, float* __restrict__ Y,
                          const int* __restrict__ dtf) {
  const int bf = get_bf(abf, dtf);
  int row = blockIdx.x, tid = threadIdx.x;
  const long base = (long)row * n;
  double s0 = 0.0, s1 = 0.0;
  for (int j = tid; j < n; j += 256) {
    double a = (double)ld1(A, bf, base + j);
    s0 += a * (double)Zs[2 * j];
    s1 += a * (double)Zs[2 * j + 1];
  }
  __shared__ double r0[256], r1[256];
  r0[tid] = s0; r1[tid] = s1; __syncthreads();
  for (int st = 128; st > 0; st >>= 1) {
    if (tid < st) { r0[tid] += r0[tid + st]; r1[tid] += r1[tid + st]; }
    __syncthreads();
  }
  if (tid == 0) { Y[2 * row] = (float)r0[0]; Y[2 * row + 1] = (float)r1[0]; }
}

__global__ void final_k(const float* __restrict__ Y, const float* __restrict__ Zs,
                        const float* __restrict__ dinv, const float* __restrict__ b2,
                        int n, float* __restrict__ out) {
  int i = blockIdx.x * 256 + threadIdx.x;
  if (i >= n) return;
  double di = dinv[i];
  double t0 = di * ((double)Y[2 * i] + 2.0 * (double)Zs[2 * i]) + (double)b2[0];
  double t1 = di * ((double)Y[2 * i + 1] + 2.0 * (double)Zs[2 * i + 1]) + (double)b2[1];
  double m = fmax(t0, t1);
  double l = m + log(exp(t0 - m) + exp(t1 - m));
  out[2 * i] = (float)(t0 - l);
  out[2 * i + 1] = (float)(t1 - l);
}

// ---------- host orchestration ----------
extern "C" void kernel_launch(void* const* d_in, const int* in_sizes, int n_in,
                              void* d_out, int out_size, void* d_ws, size_t ws_size,
                              hipStream_t stream) {
  const int N0 = 4096, H = 200;
  const int K1 = 3072, K2 = 1536, K3 = 768;

  const void* in_x = d_in[0];
  const void* adj  = d_in[1];
  const void* w0 = d_in[2];  const void* b0 = d_in[3];
  const void* w1 = d_in[4];  const void* b1 = d_in[5];
  const void* w2 = d_in[6];  const void* b2 = d_in[7];
  const void* w3 = d_in[8];  const void* b3 = d_in[9];
  const void* p1 = d_in[10]; const void* p2 = d_in[11];
  const void* p3 = d_in[12];
  const void* u0w = d_in[13]; const void* u0b = d_in[14];
  const void* u1w = d_in[15]; const void* u1b = d_in[16];
  const void* u2w = d_in[17]; const void* u2b = d_in[18];

  char* wp = (char*)d_ws;
  auto alloc = [&](size_t bytes) -> void* {
    void* p = (void*)wp;
    wp += (bytes + 255) & ~(size_t)255;
    return p;
  };
  float* As1  = (float*)alloc((size_t)K1 * K1 * 4);          // 37.7 MB
  float* As2  = (float*)alloc((size_t)K2 * K2 * 4);          // 9.4 MB
  float* A3   = (float*)alloc((size_t)K3 * K3 * 4);          // 2.4 MB
  // shared scratch: Agb (syrk staging) / parts (agg + L3 k-split) — lifetimes disjoint
  size_t scrBytes = (size_t)8 * N0 * 208 * 4;                // 27.3 MB
  void* scratchU = alloc(scrBytes);
  u16*   Agb  = (u16*)scratchU;
  float* parts = (float*)scratchU;
  u16* Ag3h = (u16*)alloc((size_t)K3 * K2 * 2);              // 2.4 MB
  u16* Ag3l = (u16*)alloc((size_t)K3 * K2 * 2);              // 2.4 MB
  u16* Ah0 = (u16*)alloc((size_t)N0 * N0 * 2);               // 33.5 MB
  u16* Ah1 = (u16*)alloc((size_t)K1 * K1 * 2);               // 18.9 MB
  u16* Ah2 = (u16*)alloc((size_t)K2 * K2 * 2);               // 4.7 MB
  u16* Al2 = (u16*)alloc((size_t)K2 * K2 * 2);               // 4.7 MB
  u16* Ah3 = (u16*)alloc((size_t)K3 * K3 * 2);               // 1.2 MB
  u16* Al3 = (u16*)alloc((size_t)K3 * K3 * 2);               // 1.2 MB
  u16* ZT  = (u16*)alloc((size_t)3 * 208 * N0 * 2);          // 5.1 MB
  float* xs0  = (float*)alloc((size_t)N0 * H * 4);
  float* xs1  = (float*)alloc((size_t)K1 * H * 4);
  float* xs2  = (float*)alloc((size_t)K2 * H * 4);
  float* xcur = (float*)alloc((size_t)N0 * H * 4);
  float* xtmp = (float*)alloc((size_t)N0 * H * 4);
  float* Zbuf = (float*)alloc((size_t)N0 * H * 4);
  float* Ybuf = (float*)alloc((size_t)N0 * 208 * 4);
  float* Xinf = (float*)alloc((size_t)N0 * 3 * 4);
  float* dinv0 = (float*)alloc((size_t)N0 * 4);
  float* dinv1 = (float*)alloc((size_t)K1 * 4);
  float* dinv2 = (float*)alloc((size_t)K2 * 4);
  float* dinv3 = (float*)alloc((size_t)K3 * 4);
  float* scores = (float*)alloc((size_t)N0 * 4);
  int* perm1 = (int*)alloc((size_t)K1 * 4);
  int* perm2 = (int*)alloc((size_t)K2 * 4);
  int* perm3 = (int*)alloc((size_t)K3 * 4);
  double* pn = (double*)alloc(8);
  int* dtflag = (int*)alloc(256);
  float* w0f = (float*)alloc(3 * H * 4);  float* b0f = (float*)alloc(H * 4);
  float* w1f = (float*)alloc(H * H * 4);  float* b1f = (float*)alloc(H * 4);
  float* w2f = (float*)alloc(H * H * 4);  float* b2f = (float*)alloc(H * 4);
  float* w3f = (float*)alloc(H * H * 4);  float* b3f = (float*)alloc(H * 4);
  float* p1f = (float*)alloc(H * 4);
  float* p2f = (float*)alloc(H * 4);
  float* p3f = (float*)alloc(H * 4);
  float* u0wf = (float*)alloc(H * H * 4); float* u0bf = (float*)alloc(H * 4);
  float* u1wf = (float*)alloc(H * H * 4); float* u1bf = (float*)alloc(H * 4);
  float* u2wf = (float*)alloc(H * 2 * 4); float* u2bf = (float*)alloc(2 * 4);
  (void)in_sizes; (void)n_in; (void)out_size; (void)ws_size;

  detect_init_k<<<dim3(1), dim3(64), 0, stream>>>(dtflag);
  detect_k<<<dim3(4096), dim3(256), 0, stream>>>((const u32*)adj, (long)N0 * N0 / 2, dtflag);

  auto up = [&](const void* s, float* d, int n) {
    upcast_k<<<dim3((n + 255) / 256), dim3(256), 0, stream>>>(s, d, n, dtflag);
  };
  up(in_x, Xinf, N0 * 3);
  up(w0, w0f, 3 * H);  up(b0, b0f, H);
  up(w1, w1f, H * H);  up(b1, b1f, H);
  up(w2, w2f, H * H);  up(b2, b2f, H);
  up(w3, w3f, H * H);  up(b3, b3f, H);
  up(p1, p1f, H); up(p2, p2f, H); up(p3, p3f, H);
  up(u0w, u0wf, H * H); up(u0b, u0bf, H);
  up(u1w, u1wf, H * H); up(u1b, u1bf, H);
  up(u2w, u2wf, H * 2); up(u2b, u2bf, 2);

  a_from_adj_k<<<dim3((unsigned)(((long)N0 * N0 + 255) / 256)), dim3(256), 0, stream>>>(
      adj, dtflag, (long)N0 * N0, Ah0);

  auto gemm64 = [&](const void* A, long lda, int abf, const void* B, long ldb, int bbf,
                    float* C, long ldc, int M, int Nn, int K) {
    dim3 g((Nn + 63) / 64, (M + 63) / 64);
    gemm64_f64<<<g, dim3(256), 0, stream>>>(A, lda, abf, B, ldb, bbf, C, ldc, M, Nn, K, dtflag);
  };

  auto gcn = [&](const u16* Ah, const u16* Al, int n, const float* dinv, const float* Xin_,
                 int din, const float* W, const float* bb, float* out, int relu) {
    gemm64(Xin_, din, 0, W, H, 0, Zbuf, H, n, H, din);
    long tot = (long)n * H;
    scale_rows_k<<<dim3((unsigned)((tot + 255) / 256)), dim3(256), 0, stream>>>(Zbuf, dinv, n, H);
    zsplit_k<<<dim3(n / 32, 7), dim3(32, 8), 0, stream>>>(Zbuf, n, H, ZT);
    agg_mfma<13><<<dim3(n / 128, 8), dim3(256), 0, stream>>>(Ah, Al, ZT, parts, n, (n / 32) / 8);
    long n208 = (long)n * 208;
    reduce8_k<<<dim3((unsigned)((n208 + 255) / 256)), dim3(256), 0, stream>>>(parts, Ybuf, n208);
    gcn_epi_k<<<dim3((unsigned)((tot + 255) / 256)), dim3(256), 0, stream>>>(
        Ybuf, Zbuf, dinv, bb, out, n, H, relu);
  };

  auto pool = [&](const float* xin, int n, int np2, int k, const float* pwf,
                  int* perm, float* xout) {
    pnorm_k<<<dim3(1), dim3(256), 0, stream>>>(pwf, H, pn);
    score_k<<<dim3(n), dim3(64), 0, stream>>>(xin, H, pwf, pn, scores);
    topk_k<<<dim3(1), dim3(1024), 0, stream>>>(scores, n, np2, k, perm);
    long tot = (long)k * H;
    gatherx_k<<<dim3((unsigned)((tot + 255) / 256)), dim3(256), 0, stream>>>(
        xin, scores, perm, k, H, xout);
  };

  // fused pooled augment via triangle SYRK (bf16 exact): dst = ((src+I)[perm] @ ..^T), diag 0
  auto fused_aug_bf = [&](const void* src, int srcbf, int nsrc, const int* perm, int k,
                          float* dst) {
    long tot = (long)k * nsrc;
    build_ag_bf_k<<<dim3((unsigned)((tot + 255) / 256)), dim3(256), 0, stream>>>(
        src, srcbf, nsrc, perm, tot, nsrc, Agb, dtflag);
    int nt = k / 128;
    syrk_tri_bf16<<<dim3(nt * (nt + 1) / 2), dim3(256), 0, stream>>>(Agb, nsrc, dst, k, nsrc);
  };
  auto asplit = [&](const float* src, long tot, u16* Ah, u16* Al) {
    asplit_k<<<dim3((unsigned)((tot + 255) / 256)), dim3(256), 0, stream>>>(src, tot, Ah, Al);
  };

  // ---------------- forward ----------------
  rowsum_dinv_k<<<dim3(N0), dim3(256), 0, stream>>>(adj, -1, N0, dinv0, dtflag);
  gcn(Ah0, nullptr, N0, dinv0, Xinf, 3, w0f, b0f, xs0, 1);

  // down 0
  pool(xs0, N0, 4096, K1, p1f, perm1, xcur);
  fused_aug_bf(adj, -1, N0, perm1, K1, As1);
  asplit(As1, (long)K1 * K1, Ah1, nullptr);
  rowsum_dinv_k<<<dim3(K1), dim3(256), 0, stream>>>(As1, 0, K1, dinv1, dtflag);
  gcn(Ah1, nullptr, K1, dinv1, xcur, H, w1f, b1f, xs1, 1);

  // down 1
  pool(xs1, K1, 4096, K2, p2f, perm2, xcur);
  fused_aug_bf(As1, 0, K1, perm2, K2, As2);
  asplit(As2, (long)K2 * K2, Ah2, Al2);
  rowsum_dinv_k<<<dim3(K2), dim3(256), 0, stream>>>(As2, 0, K2, dinv2, dtflag);
  gcn(Ah2, Al2, K2, dinv2, xcur, H, w2f, b2f, xs2, 1);

  // down 2: MFMA 2-plane K-split SYRK (integer-exact)
  pool(xs2, K2, 2048, K3, p3f, perm3, xcur);
  {
    long tot = (long)K3 * K2;
    build_ag3_split_k<<<dim3((unsigned)((tot + 255) / 256)), dim3(256), 0, stream>>>(
        As2, K2, perm3, tot, K2, Ag3h, Ag3l);
    syrk2_ks<<<dim3(K3 / 128, K3 / 128, 8), dim3(256), 0, stream>>>(
        Ag3h, Ag3l, K2, parts, K3, K2 / 8);
    long nn = (long)K3 * K3;
    reduce_sq_k<<<dim3((unsigned)((nn + 255) / 256)), dim3(256), 0, stream>>>(parts, A3, K3, 8);
  }
  asplit(A3, (long)K3 * K3, Ah3, Al3);
  rowsum_dinv_k<<<dim3(K3), dim3(256), 0, stream>>>(A3, 0, K3, dinv3, dtflag);
  gcn(Ah3, Al3, K3, dinv3, xcur, H, w3f, b3f, xcur, 1);

  // up 0: j=2
  copy_k<<<dim3((unsigned)(((long)K2 * H + 255) / 256)), dim3(256), 0, stream>>>(xs2, xtmp, (long)K2 * H);
  scatter_add_k<<<dim3((unsigned)(((long)K3 * H + 255) / 256)), dim3(256), 0, stream>>>(xtmp, perm3, xcur, K3, H);
  gcn(Ah2, Al2, K2, dinv2, xtmp, H, u0wf, u0bf, xcur, 1);

  // up 1: j=1
  copy_k<<<dim3((unsigned)(((long)K1 * H + 255) / 256)), dim3(256), 0, stream>>>(xs1, xtmp, (long)K1 * H);
  scatter_add_k<<<dim3((unsigned)(((long)K2 * H + 255) / 256)), dim3(256), 0, stream>>>(xtmp, perm2, xcur, K2, H);
  gcn(Ah1, nullptr, K1, dinv1, xtmp, H, u1wf, u1bf, xcur, 1);

  // up 2: j=0
  copy_k<<<dim3((unsigned)(((long)N0 * H + 255) / 256)), dim3(256), 0, stream>>>(xs0, xtmp, (long)N0 * H);
  scatter_add_k<<<dim3((unsigned)(((long)K1 * H + 255) / 256)), dim3(256), 0, stream>>>(xtmp, perm1, xcur, K1, H);
  gemm64(xtmp, H, 0, u2wf, 2, 0, Zbuf, 2, N0, 2, H);
  scale_rows_k<<<dim3((N0 * 2 + 255) / 256), dim3(256), 0, stream>>>(Zbuf, dinv0, N0, 2);
  matvec2_k<<<dim3(N0), dim3(256), 0, stream>>>(adj, -1, N0, Zbuf, Ybuf, dtflag);
  final_k<<<dim3((N0 + 255) / 256), dim3(256), 0, stream>>>(Ybuf, Zbuf, dinv0, u2bf, N0, (float*)d_out);
}